// Round 3
// baseline (660.161 us; speedup 1.0000x reference)
//
#include <hip/hip_runtime.h>

typedef short short8 __attribute__((ext_vector_type(8)));
typedef float f32x4 __attribute__((ext_vector_type(4)));

#define NELT 16777216  // B*S*C*D per tensor

__device__ __forceinline__ float b2f(unsigned short u) {
    return __uint_as_float(((unsigned)u) << 16);
}
__device__ __forceinline__ unsigned short f2b(float f) {
    unsigned u = __float_as_uint(f);
    u += 0x7FFF + ((u >> 16) & 1);   // RTN-even
    return (unsigned short)(u >> 16);
}
// Markidis split: f ~= b2f(hi) + b2f(lo)
__device__ __forceinline__ void split2(float f, unsigned short& hi, unsigned short& lo) {
    unsigned short h = f2b(f);
    hi = h;
    lo = f2b(f - b2f(h));
}
// row r of the (BC*S, D) flattened view -> flat offset into x (B,S,C,D)
__device__ __forceinline__ int xrow_off(int r) {
    int n = r >> 6, s = r & 63;
    int b = n >> 7, c = n & 127;
    return (((b << 6) + s) * 128 + c) << 8;
}
// XOR-swizzled LDS element offset, 32x256 bf16 half-tile, 8-elem chunks.
__device__ __forceinline__ int sw256(int row, int k) {
    return row * 256 + ((((k >> 3) ^ (row & 7)) << 3) | (k & 7));
}
// linearized B-fragment offset (in shorts): [nt][kk][ct][lq][lm][hi8|lo8]
__device__ __forceinline__ int boff(int nt, int kk, int ct, int lq, int lm) {
    return ((((nt * 8 + kk) * 4 + ct) * 4 + lq) * 16 + lm) * 16;
}

// ---- weight pre-linearization into MFMA B-fragment order (both dirs) ----
struct WArgs {
    const float* Wq[2]; const float* Wk[2]; const float* Wv[2]; const float* Wo[2];
    unsigned short* Bqkv[2]; unsigned short* Bo[2];
};
__global__ __launch_bounds__(256) void w_prep(WArgs A)
{
    const int dir = blockIdx.y;
    const int tid = blockIdx.x * 256 + threadIdx.x;
    const int lm = tid & 15, lq = (tid >> 4) & 3, ct = (tid >> 6) & 3;
    const int kk = (tid >> 8) & 7, nt = tid >> 11;
    const int c = ct * 16 + lm;
    {
        const float* W; int ldw, col;
        if (nt < 4)      { W = A.Wq[dir]; ldw = 256; col = nt * 64 + c; }
        else if (nt < 6) { W = A.Wk[dir]; ldw = 128; col = (nt - 4) * 64 + c; }
        else             { W = A.Wv[dir]; ldw = 128; col = (nt - 6) * 64 + c; }
        short8 h8, l8;
        #pragma unroll
        for (int j = 0; j < 8; ++j) {
            int k = kk * 32 + lq * 8 + j;
            unsigned short h, l;
            split2(W[k * ldw + col], h, l);
            h8[j] = (short)h; l8[j] = (short)l;
        }
        int off = boff(nt, kk, ct, lq, lm);
        *(short8*)&A.Bqkv[dir][off] = h8;
        *(short8*)&A.Bqkv[dir][off + 8] = l8;
    }
    if (nt < 4) {
        int col = nt * 64 + c;
        short8 h8, l8;
        #pragma unroll
        for (int j = 0; j < 8; ++j) {
            int k = kk * 32 + lq * 8 + j;
            unsigned short h, l;
            split2(A.Wo[dir][k * 256 + col], h, l);
            h8[j] = (short)h; l8[j] = (short)l;
        }
        int off = boff(nt, kk, ct, lq, lm);
        *(short8*)&A.Bo[dir][off] = h8;
        *(short8*)&A.Bo[dir][off + 8] = l8;
    }
}

struct FusedArgs {
    const float* xq[2];   const float* xkv[2];
    const float* gq[2];   const float* btq[2];
    const float* gkv[2];  const float* btkv[2];
    const unsigned short* Bqkv[2];
    const unsigned short* Bow[2];
    const float* bq[2];   const float* bk[2];
    const float* bv[2];   const float* bo[2];
    const float* gate[2];
    float* out[2];
};

// ======================= fully-fused per-sequence kernel ==================
// grid (1024, 2): x = sequence (b*128+c), y = direction.
// LDS = 40 KiB -> 4 blocks/CU (2x occupancy vs 64 KiB).
//   staging region: Ah/Al 32-row half-tiles (2 x 16 KiB) at [0, 32 KiB)
//   per-wave slots: 10 KiB each at [w*10 KiB, ...) -- time-multiplexed
// GEMMs run as two half-M passes over the staged half-tiles.
__global__ __launch_bounds__(256, 4) void fused(FusedArgs P_)
{
    __shared__ char SM[40960];
    unsigned short* Ah = (unsigned short*)SM;              // [32*256]
    unsigned short* Al = (unsigned short*)(SM + 16384);
    const int dir = blockIdx.y;
    const int n = blockIdx.x, t = threadIdx.x;
    const int r0 = n * 64;
    const int w = t >> 6, l = t & 63, lm = l & 15, lq = l >> 4;
    unsigned short* slot = (unsigned short*)(SM + w * 10240);  // per-wave 10 KiB

    const float* xq  = P_.xq[dir];
    const float* xkv = P_.xkv[dir];
    const unsigned short* Bq  = P_.Bqkv[dir];
    const unsigned short* BoW = P_.Bow[dir];

    // ------- staging helper: LN + split2 of 32 rows (half h) into Ah/Al ----
    auto stage_half = [&](const float* X, const float4& gv, const float4& b4, int h) {
        float4 xv[8];
        #pragma unroll
        for (int it = 0; it < 8; ++it)
            xv[it] = *(const float4*)(X + xrow_off(r0 + h * 32 + it * 4 + w) + l * 4);
        #pragma unroll
        for (int it = 0; it < 8; ++it) {
            int row = it * 4 + w;            // local row within half-tile
            float4 x4 = xv[it];
            float s1 = x4.x + x4.y + x4.z + x4.w;
            float s2 = x4.x * x4.x + x4.y * x4.y + x4.z * x4.z + x4.w * x4.w;
            #pragma unroll
            for (int m = 1; m < 64; m <<= 1) {
                s1 += __shfl_xor(s1, m);
                s2 += __shfl_xor(s2, m);
            }
            float mu = s1 * (1.f / 256.f);
            float rstd = rsqrtf(s2 * (1.f / 256.f) - mu * mu + 1e-5f);
            float v0 = (x4.x - mu) * rstd * gv.x + b4.x;
            float v1 = (x4.y - mu) * rstd * gv.y + b4.y;
            float v2 = (x4.z - mu) * rstd * gv.z + b4.z;
            float v3 = (x4.w - mu) * rstd * gv.w + b4.w;
            ushort4 oh, ol;
            split2(v0, oh.x, ol.x); split2(v1, oh.y, ol.y);
            split2(v2, oh.z, ol.z); split2(v3, oh.w, ol.w);
            *(ushort4*)&Ah[sw256(row, l * 4)] = oh;
            *(ushort4*)&Al[sw256(row, l * 4)] = ol;
        }
    };

    // ================= K,V projection (two half-M passes) =================
    f32x4 kacc[4][2] = {};
    f32x4 vacc[4][2] = {};
    {
        const float4 gv = *(const float4*)(P_.gkv[dir] + l * 4);
        const float4 b4 = *(const float4*)(P_.btkv[dir] + l * 4);
        const int ntK = 4 + (w >> 1), ntV = 6 + (w >> 1);
        #pragma unroll
        for (int h = 0; h < 2; ++h) {
            stage_half(xkv, gv, b4, h);
            __syncthreads();
            #pragma unroll
            for (int kk = 0; kk < 8; ++kk) {
                int k0 = kk * 32 + lq * 8;
                short8 ah[2], al[2];
                #pragma unroll
                for (int m2 = 0; m2 < 2; ++m2) {
                    ah[m2] = *(const short8*)&Ah[sw256(m2 * 16 + lm, k0)];
                    al[m2] = *(const short8*)&Al[sw256(m2 * 16 + lm, k0)];
                }
                #pragma unroll
                for (int i = 0; i < 2; ++i) {
                    int ct = (2 * w + i) & 3;
                    int offK = boff(ntK, kk, ct, lq, lm);
                    short8 bh = *(const short8*)&Bq[offK];
                    short8 bl = *(const short8*)&Bq[offK + 8];
                    #pragma unroll
                    for (int m2 = 0; m2 < 2; ++m2) {
                        int m = 2 * h + m2;
                        kacc[m][i] = __builtin_amdgcn_mfma_f32_16x16x32_bf16(ah[m2], bh, kacc[m][i], 0, 0, 0);
                        kacc[m][i] = __builtin_amdgcn_mfma_f32_16x16x32_bf16(al[m2], bh, kacc[m][i], 0, 0, 0);
                        kacc[m][i] = __builtin_amdgcn_mfma_f32_16x16x32_bf16(ah[m2], bl, kacc[m][i], 0, 0, 0);
                    }
                    int offV = boff(ntV, kk, ct, lq, lm);
                    bh = *(const short8*)&Bq[offV];
                    bl = *(const short8*)&Bq[offV + 8];
                    #pragma unroll
                    for (int m2 = 0; m2 < 2; ++m2) {
                        int m = 2 * h + m2;
                        vacc[m][i] = __builtin_amdgcn_mfma_f32_16x16x32_bf16(ah[m2], bh, vacc[m][i], 0, 0, 0);
                        vacc[m][i] = __builtin_amdgcn_mfma_f32_16x16x32_bf16(al[m2], bh, vacc[m][i], 0, 0, 0);
                        vacc[m][i] = __builtin_amdgcn_mfma_f32_16x16x32_bf16(ah[m2], bl, vacc[m][i], 0, 0, 0);
                    }
                }
            }
            __syncthreads();
        }
    }

    // ====== K/V repack (wave-local) C-layout -> frag layout ======
    // Kslot [64 keys][stride 40]; Vslot = V^T [32 dims][stride 72]
    unsigned short* Ks = slot;
    unsigned short* Vs = slot + 2560;
    {
        float bkv0 = P_.bk[dir][w * 32 + lm],  bkv1 = P_.bk[dir][w * 32 + 16 + lm];
        float bvv0 = P_.bv[dir][w * 32 + lm],  bvv1 = P_.bv[dir][w * 32 + 16 + lm];
        #pragma unroll
        for (int m = 0; m < 4; ++m) {
            #pragma unroll
            for (int rg = 0; rg < 4; ++rg) {
                int key = m * 16 + lq * 4 + rg;
                Ks[key * 40 + lm]      = f2b(kacc[m][0][rg] + bkv0);
                Ks[key * 40 + 16 + lm] = f2b(kacc[m][1][rg] + bkv1);
                Vs[lm * 72 + key]        = f2b(vacc[m][0][rg] + bvv0);
                Vs[(16 + lm) * 72 + key] = f2b(vacc[m][1][rg] + bvv1);
            }
        }
    }
    short8 kf[4];
    #pragma unroll
    for (int nt = 0; nt < 4; ++nt)
        kf[nt] = *(const short8*)&Ks[(nt * 16 + lm) * 40 + lq * 8];
    short8 vb[2][2];
    #pragma unroll
    for (int kt = 0; kt < 2; ++kt) {
        vb[kt][0] = *(const short8*)&Vs[lm * 72 + kt * 32 + lq * 8];
        vb[kt][1] = *(const short8*)&Vs[(16 + lm) * 72 + kt * 32 + lq * 8];
    }
    __syncthreads();   // frags in regs; LDS free for xq staging

    // ================= Q projection (two half-M passes) =================
    f32x4 qacc[4][4] = {};
    {
        const float4 gv = *(const float4*)(P_.gq[dir] + l * 4);
        const float4 b4 = *(const float4*)(P_.btq[dir] + l * 4);
        #pragma unroll
        for (int h = 0; h < 2; ++h) {
            stage_half(xq, gv, b4, h);
            __syncthreads();
            #pragma unroll
            for (int kk = 0; kk < 8; ++kk) {
                int k0 = kk * 32 + lq * 8;
                short8 ah[2], al[2];
                #pragma unroll
                for (int m2 = 0; m2 < 2; ++m2) {
                    ah[m2] = *(const short8*)&Ah[sw256(m2 * 16 + lm, k0)];
                    al[m2] = *(const short8*)&Al[sw256(m2 * 16 + lm, k0)];
                }
                #pragma unroll
                for (int i = 0; i < 4; ++i) {
                    int off = boff(w, kk, i, lq, lm);
                    short8 bh = *(const short8*)&Bq[off];
                    short8 bl = *(const short8*)&Bq[off + 8];
                    #pragma unroll
                    for (int m2 = 0; m2 < 2; ++m2) {
                        int m = 2 * h + m2;
                        qacc[m][i] = __builtin_amdgcn_mfma_f32_16x16x32_bf16(ah[m2], bh, qacc[m][i], 0, 0, 0);
                        qacc[m][i] = __builtin_amdgcn_mfma_f32_16x16x32_bf16(al[m2], bh, qacc[m][i], 0, 0, 0);
                        qacc[m][i] = __builtin_amdgcn_mfma_f32_16x16x32_bf16(ah[m2], bl, qacc[m][i], 0, 0, 0);
                    }
                }
            }
            __syncthreads();
        }
    }

    // ====== Q repack (wave-local), then attention ======
    unsigned short* Qs = slot;
    {
        float bq0 = P_.bq[dir][w * 64 + lm],      bq1 = P_.bq[dir][w * 64 + 16 + lm];
        float bq2 = P_.bq[dir][w * 64 + 32 + lm], bq3 = P_.bq[dir][w * 64 + 48 + lm];
        #pragma unroll
        for (int m = 0; m < 4; ++m) {
            #pragma unroll
            for (int rg = 0; rg < 4; ++rg) {
                int row = (m * 16 + lq * 4 + rg) * 72;
                Qs[row + lm]      = f2b(qacc[m][0][rg] + bq0);
                Qs[row + 16 + lm] = f2b(qacc[m][1][rg] + bq1);
                Qs[row + 32 + lm] = f2b(qacc[m][2][rg] + bq2);
                Qs[row + 48 + lm] = f2b(qacc[m][3][rg] + bq3);
            }
        }
    }
    short8 qf[2][4];
    #pragma unroll
    for (int hi = 0; hi < 2; ++hi)
        #pragma unroll
        for (int mt = 0; mt < 4; ++mt)
            qf[hi][mt] = *(const short8*)&Qs[(mt * 16 + lm) * 72 + hi * 32 + lq * 8];

    unsigned short* Pw = slot;   // overwrites Q bytes (qf already in regs)
    const float scale = 0.17677669529663687f;    // 1/sqrt(32)
    f32x4 o[2][4][2] = {};
    #pragma unroll
    for (int hi = 0; hi < 2; ++hi) {
        f32x4 s[4][4];
        #pragma unroll
        for (int mt = 0; mt < 4; ++mt) {
            #pragma unroll
            for (int nt = 0; nt < 4; ++nt) {
                f32x4 z = {0, 0, 0, 0};
                s[mt][nt] = __builtin_amdgcn_mfma_f32_16x16x32_bf16(qf[hi][mt], kf[nt], z, 0, 0, 0);
            }
        }
        #pragma unroll
        for (int mt = 0; mt < 4; ++mt) {
            #pragma unroll
            for (int rg = 0; rg < 4; ++rg) {
                float mx = fmaxf(fmaxf(s[mt][0][rg], s[mt][1][rg]),
                                 fmaxf(s[mt][2][rg], s[mt][3][rg]));
                #pragma unroll
                for (int msk = 1; msk < 16; msk <<= 1)
                    mx = fmaxf(mx, __shfl_xor(mx, msk));
                float p0 = __expf((s[mt][0][rg] - mx) * scale);
                float p1 = __expf((s[mt][1][rg] - mx) * scale);
                float p2 = __expf((s[mt][2][rg] - mx) * scale);
                float p3 = __expf((s[mt][3][rg] - mx) * scale);
                float sum = p0 + p1 + p2 + p3;
                #pragma unroll
                for (int msk = 1; msk < 16; msk <<= 1)
                    sum += __shfl_xor(sum, msk);
                float inv = 1.f / sum;
                int rowb = (mt * 16 + lq * 4 + rg) * 72 + lm;
                Pw[rowb + 0]  = f2b(p0 * inv);
                Pw[rowb + 16] = f2b(p1 * inv);
                Pw[rowb + 32] = f2b(p2 * inv);
                Pw[rowb + 48] = f2b(p3 * inv);
            }
        }
        #pragma unroll
        for (int kt = 0; kt < 2; ++kt) {
            #pragma unroll
            for (int mt = 0; mt < 4; ++mt) {
                short8 pa = *(const short8*)&Pw[(mt * 16 + lm) * 72 + kt * 32 + lq * 8];
                o[hi][mt][0] = __builtin_amdgcn_mfma_f32_16x16x32_bf16(pa, vb[kt][0], o[hi][mt][0], 0, 0, 0);
                o[hi][mt][1] = __builtin_amdgcn_mfma_f32_16x16x32_bf16(pa, vb[kt][1], o[hi][mt][1], 0, 0, 0);
            }
        }
    }
    __syncthreads();   // all waves done with slots; LDS free for attn-out

    // ====== O-projection (two half-M passes) + gate + residual ======
    f32x4 acc[4][4] = {};
    #pragma unroll
    for (int h = 0; h < 2; ++h) {
        // stage attn-out rows of this half (mt = 2h, 2h+1) as split bf16
        #pragma unroll
        for (int m2 = 0; m2 < 2; ++m2) {
            int mt = 2 * h + m2;
            #pragma unroll
            for (int hi = 0; hi < 2; ++hi) {
                #pragma unroll
                for (int n2 = 0; n2 < 2; ++n2) {
                    #pragma unroll
                    for (int rg = 0; rg < 4; ++rg) {
                        int row = m2 * 16 + lq * 4 + rg;    // local row
                        int col = w * 64 + hi * 32 + n2 * 16 + lm;
                        unsigned short h_, l_;
                        split2(o[hi][mt][n2][rg], h_, l_);
                        int sw = sw256(row, col);
                        Ah[sw] = h_;
                        Al[sw] = l_;
                    }
                }
            }
        }
        __syncthreads();
        #pragma unroll
        for (int kk = 0; kk < 8; ++kk) {
            int k0 = kk * 32 + lq * 8;
            short8 ah[2], al[2];
            #pragma unroll
            for (int m2 = 0; m2 < 2; ++m2) {
                ah[m2] = *(const short8*)&Ah[sw256(m2 * 16 + lm, k0)];
                al[m2] = *(const short8*)&Al[sw256(m2 * 16 + lm, k0)];
            }
            #pragma unroll
            for (int i = 0; i < 4; ++i) {
                int off = boff(w, kk, i, lq, lm);
                short8 bh = *(const short8*)&BoW[off];
                short8 bl = *(const short8*)&BoW[off + 8];
                #pragma unroll
                for (int m2 = 0; m2 < 2; ++m2) {
                    int m = 2 * h + m2;
                    acc[m][i] = __builtin_amdgcn_mfma_f32_16x16x32_bf16(ah[m2], bh, acc[m][i], 0, 0, 0);
                    acc[m][i] = __builtin_amdgcn_mfma_f32_16x16x32_bf16(al[m2], bh, acc[m][i], 0, 0, 0);
                    acc[m][i] = __builtin_amdgcn_mfma_f32_16x16x32_bf16(ah[m2], bl, acc[m][i], 0, 0, 0);
                }
            }
        }
        __syncthreads();
    }
    float sig = 1.f / (1.f + __expf(-P_.gate[dir][0]));
    const float* Xres = xq;
    float* Out = P_.out[dir];
    #pragma unroll
    for (int i = 0; i < 4; ++i) {
        int col = w * 64 + i * 16 + lm;
        float bias = P_.bo[dir][col];
        #pragma unroll
        for (int m = 0; m < 4; ++m) {
            #pragma unroll
            for (int rg = 0; rg < 4; ++rg) {
                int row = m * 16 + lq * 4 + rg;
                int oidx = xrow_off(r0 + row) + col;
                Out[oidx] = Xres[oidx] + sig * (acc[m][i][rg] + bias);
            }
        }
    }
}

extern "C" void kernel_launch(void* const* d_in, const int* in_sizes, int n_in,
                              void* d_out, int out_size, void* d_ws, size_t ws_size,
                              hipStream_t stream) {
    const float* x_spec = (const float*)d_in[0];
    const float* x_spat = (const float*)d_in[1];
    const float* ln_g[4] = {(const float*)d_in[2], (const float*)d_in[4],
                            (const float*)d_in[6], (const float*)d_in[8]};
    const float* ln_b[4] = {(const float*)d_in[3], (const float*)d_in[5],
                            (const float*)d_in[7], (const float*)d_in[9]};
    char* ws = (char*)d_ws;
    unsigned short* Bqkv[2] = {(unsigned short*)ws,
                               (unsigned short*)(ws + (512 << 10))};     // 2 x 512 KiB
    unsigned short* BoL[2]  = {(unsigned short*)(ws + (1024 << 10)),
                               (unsigned short*)(ws + (1280 << 10))};    // 2 x 256 KiB

    WArgs WA;
    for (int dir = 0; dir < 2; ++dir) {
        int base = 10 + dir * 8;
        WA.Wq[dir] = (const float*)d_in[base + 0];
        WA.Wk[dir] = (const float*)d_in[base + 2];
        WA.Wv[dir] = (const float*)d_in[base + 4];
        WA.Wo[dir] = (const float*)d_in[base + 6];
        WA.Bqkv[dir] = Bqkv[dir];
        WA.Bo[dir]   = BoL[dir];
    }
    w_prep<<<dim3(64, 2), 256, 0, stream>>>(WA);

    FusedArgs A;
    for (int dir = 0; dir < 2; ++dir) {
        int base = 10 + dir * 8;
        A.xq[dir]   = dir == 0 ? x_spec : x_spat;
        A.xkv[dir]  = dir == 0 ? x_spat : x_spec;
        A.gq[dir]   = dir == 0 ? ln_g[0] : ln_g[2];
        A.btq[dir]  = dir == 0 ? ln_b[0] : ln_b[2];
        A.gkv[dir]  = dir == 0 ? ln_g[3] : ln_g[1];
        A.btkv[dir] = dir == 0 ? ln_b[3] : ln_b[1];
        A.Bqkv[dir] = Bqkv[dir];
        A.Bow[dir]  = BoL[dir];
        A.bq[dir]   = (const float*)d_in[base + 1];
        A.bk[dir]   = (const float*)d_in[base + 3];
        A.bv[dir]   = (const float*)d_in[base + 5];
        A.bo[dir]   = (const float*)d_in[base + 7];
        A.gate[dir] = (const float*)d_in[26 + dir];
        A.out[dir]  = (float*)d_out + (size_t)dir * NELT;
    }
    fused<<<dim3(1024, 2), 256, 0, stream>>>(A);
}

// Round 4
// 562.354 us; speedup vs baseline: 1.1739x; 1.1739x over previous
//
#include <hip/hip_runtime.h>

typedef short short8 __attribute__((ext_vector_type(8)));
typedef float f32x4 __attribute__((ext_vector_type(4)));

#define NELT 16777216  // B*S*C*D per tensor

__device__ __forceinline__ float b2f(unsigned short u) {
    return __uint_as_float(((unsigned)u) << 16);
}
__device__ __forceinline__ unsigned short f2b(float f) {
    unsigned u = __float_as_uint(f);
    u += 0x7FFF + ((u >> 16) & 1);   // RTN-even
    return (unsigned short)(u >> 16);
}
// Markidis split: f ~= b2f(hi) + b2f(lo)
__device__ __forceinline__ void split2(float f, unsigned short& hi, unsigned short& lo) {
    unsigned short h = f2b(f);
    hi = h;
    lo = f2b(f - b2f(h));
}
// row r of the (BC*S, D) flattened view -> flat offset into x (B,S,C,D)
__device__ __forceinline__ int xrow_off(int r) {
    int n = r >> 6, s = r & 63;
    int b = n >> 7, c = n & 127;
    return (((b << 6) + s) * 128 + c) << 8;
}
// XOR-swizzled LDS element offset, 32x256 bf16 half-tile, 8-elem chunks.
__device__ __forceinline__ int sw256(int row, int k) {
    return row * 256 + ((((k >> 3) ^ (row & 7)) << 3) | (k & 7));
}
// linearized B-fragment offset (in shorts): [nt][kk][ct][lq][lm][hi8|lo8]
__device__ __forceinline__ int boff(int nt, int kk, int ct, int lq, int lm) {
    return ((((nt * 8 + kk) * 4 + ct) * 4 + lq) * 16 + lm) * 16;
}

// ---- weight pre-linearization into MFMA B-fragment order (both dirs) ----
struct WArgs {
    const float* Wq[2]; const float* Wk[2]; const float* Wv[2]; const float* Wo[2];
    unsigned short* Bqkv[2]; unsigned short* Bo[2];
};
__global__ __launch_bounds__(256) void w_prep(WArgs A)
{
    const int dir = blockIdx.y;
    const int tid = blockIdx.x * 256 + threadIdx.x;
    const int lm = tid & 15, lq = (tid >> 4) & 3, ct = (tid >> 6) & 3;
    const int kk = (tid >> 8) & 7, nt = tid >> 11;
    const int c = ct * 16 + lm;
    {
        const float* W; int ldw, col;
        if (nt < 4)      { W = A.Wq[dir]; ldw = 256; col = nt * 64 + c; }
        else if (nt < 6) { W = A.Wk[dir]; ldw = 128; col = (nt - 4) * 64 + c; }
        else             { W = A.Wv[dir]; ldw = 128; col = (nt - 6) * 64 + c; }
        short8 h8, l8;
        #pragma unroll
        for (int j = 0; j < 8; ++j) {
            int k = kk * 32 + lq * 8 + j;
            unsigned short h, l;
            split2(W[k * ldw + col], h, l);
            h8[j] = (short)h; l8[j] = (short)l;
        }
        int off = boff(nt, kk, ct, lq, lm);
        *(short8*)&A.Bqkv[dir][off] = h8;
        *(short8*)&A.Bqkv[dir][off + 8] = l8;
    }
    if (nt < 4) {
        int col = nt * 64 + c;
        short8 h8, l8;
        #pragma unroll
        for (int j = 0; j < 8; ++j) {
            int k = kk * 32 + lq * 8 + j;
            unsigned short h, l;
            split2(A.Wo[dir][k * 256 + col], h, l);
            h8[j] = (short)h; l8[j] = (short)l;
        }
        int off = boff(nt, kk, ct, lq, lm);
        *(short8*)&A.Bo[dir][off] = h8;
        *(short8*)&A.Bo[dir][off + 8] = l8;
    }
}

struct FusedArgs {
    const float* xq[2];   const float* xkv[2];
    const float* gq[2];   const float* btq[2];
    const float* gkv[2];  const float* btkv[2];
    const unsigned short* Bqkv[2];
    const unsigned short* Bow[2];
    const float* bq[2];   const float* bk[2];
    const float* bv[2];   const float* bo[2];
    const float* gate[2];
    float* out[2];
};

// ======================= fully-fused per-sequence kernel ==================
// grid (1024, 2): x = sequence (b*128+c), y = direction.
// LDS = 40 KiB -> 4 blocks/CU (LDS-capped). VGPR must stay <= 128 for the
// HW to actually schedule 4 waves/SIMD; launch_bounds(256,2) (NOT ,4 --
// that clamps the allocator to the 64-VGPR step and spills ~600 MB to
// scratch, R3 post-mortem).
__global__ __launch_bounds__(256, 2) void fused(FusedArgs P_)
{
    __shared__ char SM[40960];
    unsigned short* Ah = (unsigned short*)SM;              // [32*256]
    unsigned short* Al = (unsigned short*)(SM + 16384);
    const int dir = blockIdx.y;
    const int n = blockIdx.x, t = threadIdx.x;
    const int r0 = n * 64;
    const int w = t >> 6, l = t & 63, lm = l & 15, lq = l >> 4;
    unsigned short* slot = (unsigned short*)(SM + w * 10240);  // per-wave 10 KiB

    const float* xq  = P_.xq[dir];
    const float* xkv = P_.xkv[dir];
    const unsigned short* Bq  = P_.Bqkv[dir];
    const unsigned short* BoW = P_.Bow[dir];

    // ------- staging helper: LN + split2 of 32 rows (half h) into Ah/Al ----
    auto stage_half = [&](const float* X, const float4& gv, const float4& b4, int h) {
        float4 xv[8];
        #pragma unroll
        for (int it = 0; it < 8; ++it)
            xv[it] = *(const float4*)(X + xrow_off(r0 + h * 32 + it * 4 + w) + l * 4);
        #pragma unroll
        for (int it = 0; it < 8; ++it) {
            int row = it * 4 + w;            // local row within half-tile
            float4 x4 = xv[it];
            float s1 = x4.x + x4.y + x4.z + x4.w;
            float s2 = x4.x * x4.x + x4.y * x4.y + x4.z * x4.z + x4.w * x4.w;
            #pragma unroll
            for (int m = 1; m < 64; m <<= 1) {
                s1 += __shfl_xor(s1, m);
                s2 += __shfl_xor(s2, m);
            }
            float mu = s1 * (1.f / 256.f);
            float rstd = rsqrtf(s2 * (1.f / 256.f) - mu * mu + 1e-5f);
            float v0 = (x4.x - mu) * rstd * gv.x + b4.x;
            float v1 = (x4.y - mu) * rstd * gv.y + b4.y;
            float v2 = (x4.z - mu) * rstd * gv.z + b4.z;
            float v3 = (x4.w - mu) * rstd * gv.w + b4.w;
            ushort4 oh, ol;
            split2(v0, oh.x, ol.x); split2(v1, oh.y, ol.y);
            split2(v2, oh.z, ol.z); split2(v3, oh.w, ol.w);
            *(ushort4*)&Ah[sw256(row, l * 4)] = oh;
            *(ushort4*)&Al[sw256(row, l * 4)] = ol;
        }
    };

    // ================= K,V projection (two half-M passes) =================
    f32x4 kacc[4][2] = {};
    f32x4 vacc[4][2] = {};
    {
        const float4 gv = *(const float4*)(P_.gkv[dir] + l * 4);
        const float4 b4 = *(const float4*)(P_.btkv[dir] + l * 4);
        const int ntK = 4 + (w >> 1), ntV = 6 + (w >> 1);
        #pragma unroll
        for (int h = 0; h < 2; ++h) {
            stage_half(xkv, gv, b4, h);
            __syncthreads();
            #pragma unroll
            for (int kk = 0; kk < 8; ++kk) {
                int k0 = kk * 32 + lq * 8;
                short8 ah[2], al[2];
                #pragma unroll
                for (int m2 = 0; m2 < 2; ++m2) {
                    ah[m2] = *(const short8*)&Ah[sw256(m2 * 16 + lm, k0)];
                    al[m2] = *(const short8*)&Al[sw256(m2 * 16 + lm, k0)];
                }
                #pragma unroll
                for (int i = 0; i < 2; ++i) {
                    int ct = (2 * w + i) & 3;
                    int offK = boff(ntK, kk, ct, lq, lm);
                    short8 bh = *(const short8*)&Bq[offK];
                    short8 bl = *(const short8*)&Bq[offK + 8];
                    #pragma unroll
                    for (int m2 = 0; m2 < 2; ++m2) {
                        int m = 2 * h + m2;
                        kacc[m][i] = __builtin_amdgcn_mfma_f32_16x16x32_bf16(ah[m2], bh, kacc[m][i], 0, 0, 0);
                        kacc[m][i] = __builtin_amdgcn_mfma_f32_16x16x32_bf16(al[m2], bh, kacc[m][i], 0, 0, 0);
                        kacc[m][i] = __builtin_amdgcn_mfma_f32_16x16x32_bf16(ah[m2], bl, kacc[m][i], 0, 0, 0);
                    }
                    int offV = boff(ntV, kk, ct, lq, lm);
                    bh = *(const short8*)&Bq[offV];
                    bl = *(const short8*)&Bq[offV + 8];
                    #pragma unroll
                    for (int m2 = 0; m2 < 2; ++m2) {
                        int m = 2 * h + m2;
                        vacc[m][i] = __builtin_amdgcn_mfma_f32_16x16x32_bf16(ah[m2], bh, vacc[m][i], 0, 0, 0);
                        vacc[m][i] = __builtin_amdgcn_mfma_f32_16x16x32_bf16(al[m2], bh, vacc[m][i], 0, 0, 0);
                        vacc[m][i] = __builtin_amdgcn_mfma_f32_16x16x32_bf16(ah[m2], bl, vacc[m][i], 0, 0, 0);
                    }
                }
            }
            __syncthreads();
        }
    }

    // ====== K/V repack (wave-local) C-layout -> frag layout ======
    // Kslot [64 keys][stride 40]; Vslot = V^T [32 dims][stride 72]
    unsigned short* Ks = slot;
    unsigned short* Vs = slot + 2560;
    {
        float bkv0 = P_.bk[dir][w * 32 + lm],  bkv1 = P_.bk[dir][w * 32 + 16 + lm];
        float bvv0 = P_.bv[dir][w * 32 + lm],  bvv1 = P_.bv[dir][w * 32 + 16 + lm];
        #pragma unroll
        for (int m = 0; m < 4; ++m) {
            #pragma unroll
            for (int rg = 0; rg < 4; ++rg) {
                int key = m * 16 + lq * 4 + rg;
                Ks[key * 40 + lm]      = f2b(kacc[m][0][rg] + bkv0);
                Ks[key * 40 + 16 + lm] = f2b(kacc[m][1][rg] + bkv1);
                Vs[lm * 72 + key]        = f2b(vacc[m][0][rg] + bvv0);
                Vs[(16 + lm) * 72 + key] = f2b(vacc[m][1][rg] + bvv1);
            }
        }
    }
    short8 kf[4];
    #pragma unroll
    for (int nt = 0; nt < 4; ++nt)
        kf[nt] = *(const short8*)&Ks[(nt * 16 + lm) * 40 + lq * 8];
    short8 vb[2][2];
    #pragma unroll
    for (int kt = 0; kt < 2; ++kt) {
        vb[kt][0] = *(const short8*)&Vs[lm * 72 + kt * 32 + lq * 8];
        vb[kt][1] = *(const short8*)&Vs[(16 + lm) * 72 + kt * 32 + lq * 8];
    }
    __syncthreads();   // frags in regs; LDS free for xq staging

    // ================= Q projection (two half-M passes) =================
    f32x4 qacc[4][4] = {};
    {
        const float4 gv = *(const float4*)(P_.gq[dir] + l * 4);
        const float4 b4 = *(const float4*)(P_.btq[dir] + l * 4);
        #pragma unroll
        for (int h = 0; h < 2; ++h) {
            stage_half(xq, gv, b4, h);
            __syncthreads();
            #pragma unroll
            for (int kk = 0; kk < 8; ++kk) {
                int k0 = kk * 32 + lq * 8;
                short8 ah[2], al[2];
                #pragma unroll
                for (int m2 = 0; m2 < 2; ++m2) {
                    ah[m2] = *(const short8*)&Ah[sw256(m2 * 16 + lm, k0)];
                    al[m2] = *(const short8*)&Al[sw256(m2 * 16 + lm, k0)];
                }
                #pragma unroll
                for (int i = 0; i < 4; ++i) {
                    int off = boff(w, kk, i, lq, lm);
                    short8 bh = *(const short8*)&Bq[off];
                    short8 bl = *(const short8*)&Bq[off + 8];
                    #pragma unroll
                    for (int m2 = 0; m2 < 2; ++m2) {
                        int m = 2 * h + m2;
                        qacc[m][i] = __builtin_amdgcn_mfma_f32_16x16x32_bf16(ah[m2], bh, qacc[m][i], 0, 0, 0);
                        qacc[m][i] = __builtin_amdgcn_mfma_f32_16x16x32_bf16(al[m2], bh, qacc[m][i], 0, 0, 0);
                        qacc[m][i] = __builtin_amdgcn_mfma_f32_16x16x32_bf16(ah[m2], bl, qacc[m][i], 0, 0, 0);
                    }
                }
            }
            __syncthreads();
        }
    }

    // ====== Q repack (wave-local), then attention ======
    unsigned short* Qs = slot;
    {
        float bq0 = P_.bq[dir][w * 64 + lm],      bq1 = P_.bq[dir][w * 64 + 16 + lm];
        float bq2 = P_.bq[dir][w * 64 + 32 + lm], bq3 = P_.bq[dir][w * 64 + 48 + lm];
        #pragma unroll
        for (int m = 0; m < 4; ++m) {
            #pragma unroll
            for (int rg = 0; rg < 4; ++rg) {
                int row = (m * 16 + lq * 4 + rg) * 72;
                Qs[row + lm]      = f2b(qacc[m][0][rg] + bq0);
                Qs[row + 16 + lm] = f2b(qacc[m][1][rg] + bq1);
                Qs[row + 32 + lm] = f2b(qacc[m][2][rg] + bq2);
                Qs[row + 48 + lm] = f2b(qacc[m][3][rg] + bq3);
            }
        }
    }
    short8 qf[2][4];
    #pragma unroll
    for (int hi = 0; hi < 2; ++hi)
        #pragma unroll
        for (int mt = 0; mt < 4; ++mt)
            qf[hi][mt] = *(const short8*)&Qs[(mt * 16 + lm) * 72 + hi * 32 + lq * 8];

    unsigned short* Pw = slot;   // overwrites Q bytes (qf already in regs)
    const float scale = 0.17677669529663687f;    // 1/sqrt(32)
    f32x4 o[2][4][2] = {};
    #pragma unroll
    for (int hi = 0; hi < 2; ++hi) {
        f32x4 s[4][4];
        #pragma unroll
        for (int mt = 0; mt < 4; ++mt) {
            #pragma unroll
            for (int nt = 0; nt < 4; ++nt) {
                f32x4 z = {0, 0, 0, 0};
                s[mt][nt] = __builtin_amdgcn_mfma_f32_16x16x32_bf16(qf[hi][mt], kf[nt], z, 0, 0, 0);
            }
        }
        #pragma unroll
        for (int mt = 0; mt < 4; ++mt) {
            #pragma unroll
            for (int rg = 0; rg < 4; ++rg) {
                float mx = fmaxf(fmaxf(s[mt][0][rg], s[mt][1][rg]),
                                 fmaxf(s[mt][2][rg], s[mt][3][rg]));
                #pragma unroll
                for (int msk = 1; msk < 16; msk <<= 1)
                    mx = fmaxf(mx, __shfl_xor(mx, msk));
                float p0 = __expf((s[mt][0][rg] - mx) * scale);
                float p1 = __expf((s[mt][1][rg] - mx) * scale);
                float p2 = __expf((s[mt][2][rg] - mx) * scale);
                float p3 = __expf((s[mt][3][rg] - mx) * scale);
                float sum = p0 + p1 + p2 + p3;
                #pragma unroll
                for (int msk = 1; msk < 16; msk <<= 1)
                    sum += __shfl_xor(sum, msk);
                float inv = 1.f / sum;
                int rowb = (mt * 16 + lq * 4 + rg) * 72 + lm;
                Pw[rowb + 0]  = f2b(p0 * inv);
                Pw[rowb + 16] = f2b(p1 * inv);
                Pw[rowb + 32] = f2b(p2 * inv);
                Pw[rowb + 48] = f2b(p3 * inv);
            }
        }
        #pragma unroll
        for (int kt = 0; kt < 2; ++kt) {
            #pragma unroll
            for (int mt = 0; mt < 4; ++mt) {
                short8 pa = *(const short8*)&Pw[(mt * 16 + lm) * 72 + kt * 32 + lq * 8];
                o[hi][mt][0] = __builtin_amdgcn_mfma_f32_16x16x32_bf16(pa, vb[kt][0], o[hi][mt][0], 0, 0, 0);
                o[hi][mt][1] = __builtin_amdgcn_mfma_f32_16x16x32_bf16(pa, vb[kt][1], o[hi][mt][1], 0, 0, 0);
            }
        }
    }
    __syncthreads();   // all waves done with slots; LDS free for attn-out

    // ====== O-projection (two half-M passes) + gate + residual ======
    f32x4 acc[4][4] = {};
    #pragma unroll
    for (int h = 0; h < 2; ++h) {
        // stage attn-out rows of this half (mt = 2h, 2h+1) as split bf16
        #pragma unroll
        for (int m2 = 0; m2 < 2; ++m2) {
            int mt = 2 * h + m2;
            #pragma unroll
            for (int hi = 0; hi < 2; ++hi) {
                #pragma unroll
                for (int n2 = 0; n2 < 2; ++n2) {
                    #pragma unroll
                    for (int rg = 0; rg < 4; ++rg) {
                        int row = m2 * 16 + lq * 4 + rg;    // local row
                        int col = w * 64 + hi * 32 + n2 * 16 + lm;
                        unsigned short h_, l_;
                        split2(o[hi][mt][n2][rg], h_, l_);
                        int sw = sw256(row, col);
                        Ah[sw] = h_;
                        Al[sw] = l_;
                    }
                }
            }
        }
        __syncthreads();
        #pragma unroll
        for (int kk = 0; kk < 8; ++kk) {
            int k0 = kk * 32 + lq * 8;
            short8 ah[2], al[2];
            #pragma unroll
            for (int m2 = 0; m2 < 2; ++m2) {
                ah[m2] = *(const short8*)&Ah[sw256(m2 * 16 + lm, k0)];
                al[m2] = *(const short8*)&Al[sw256(m2 * 16 + lm, k0)];
            }
            #pragma unroll
            for (int i = 0; i < 4; ++i) {
                int off = boff(w, kk, i, lq, lm);
                short8 bh = *(const short8*)&BoW[off];
                short8 bl = *(const short8*)&BoW[off + 8];
                #pragma unroll
                for (int m2 = 0; m2 < 2; ++m2) {
                    int m = 2 * h + m2;
                    acc[m][i] = __builtin_amdgcn_mfma_f32_16x16x32_bf16(ah[m2], bh, acc[m][i], 0, 0, 0);
                    acc[m][i] = __builtin_amdgcn_mfma_f32_16x16x32_bf16(al[m2], bh, acc[m][i], 0, 0, 0);
                    acc[m][i] = __builtin_amdgcn_mfma_f32_16x16x32_bf16(ah[m2], bl, acc[m][i], 0, 0, 0);
                }
            }
        }
        __syncthreads();
    }
    float sig = 1.f / (1.f + __expf(-P_.gate[dir][0]));
    const float* Xres = xq;
    float* Out = P_.out[dir];
    #pragma unroll
    for (int i = 0; i < 4; ++i) {
        int col = w * 64 + i * 16 + lm;
        float bias = P_.bo[dir][col];
        #pragma unroll
        for (int m = 0; m < 4; ++m) {
            #pragma unroll
            for (int rg = 0; rg < 4; ++rg) {
                int row = m * 16 + lq * 4 + rg;
                int oidx = xrow_off(r0 + row) + col;
                Out[oidx] = Xres[oidx] + sig * (acc[m][i][rg] + bias);
            }
        }
    }
}

extern "C" void kernel_launch(void* const* d_in, const int* in_sizes, int n_in,
                              void* d_out, int out_size, void* d_ws, size_t ws_size,
                              hipStream_t stream) {
    const float* x_spec = (const float*)d_in[0];
    const float* x_spat = (const float*)d_in[1];
    const float* ln_g[4] = {(const float*)d_in[2], (const float*)d_in[4],
                            (const float*)d_in[6], (const float*)d_in[8]};
    const float* ln_b[4] = {(const float*)d_in[3], (const float*)d_in[5],
                            (const float*)d_in[7], (const float*)d_in[9]};
    char* ws = (char*)d_ws;
    unsigned short* Bqkv[2] = {(unsigned short*)ws,
                               (unsigned short*)(ws + (512 << 10))};     // 2 x 512 KiB
    unsigned short* BoL[2]  = {(unsigned short*)(ws + (1024 << 10)),
                               (unsigned short*)(ws + (1280 << 10))};    // 2 x 256 KiB

    WArgs WA;
    for (int dir = 0; dir < 2; ++dir) {
        int base = 10 + dir * 8;
        WA.Wq[dir] = (const float*)d_in[base + 0];
        WA.Wk[dir] = (const float*)d_in[base + 2];
        WA.Wv[dir] = (const float*)d_in[base + 4];
        WA.Wo[dir] = (const float*)d_in[base + 6];
        WA.Bqkv[dir] = Bqkv[dir];
        WA.Bo[dir]   = BoL[dir];
    }
    w_prep<<<dim3(64, 2), 256, 0, stream>>>(WA);

    FusedArgs A;
    for (int dir = 0; dir < 2; ++dir) {
        int base = 10 + dir * 8;
        A.xq[dir]   = dir == 0 ? x_spec : x_spat;
        A.xkv[dir]  = dir == 0 ? x_spat : x_spec;
        A.gq[dir]   = dir == 0 ? ln_g[0] : ln_g[2];
        A.btq[dir]  = dir == 0 ? ln_b[0] : ln_b[2];
        A.gkv[dir]  = dir == 0 ? ln_g[3] : ln_g[1];
        A.btkv[dir] = dir == 0 ? ln_b[3] : ln_b[1];
        A.Bqkv[dir] = Bqkv[dir];
        A.Bow[dir]  = BoL[dir];
        A.bq[dir]   = (const float*)d_in[base + 1];
        A.bk[dir]   = (const float*)d_in[base + 3];
        A.bv[dir]   = (const float*)d_in[base + 5];
        A.bo[dir]   = (const float*)d_in[base + 7];
        A.gate[dir] = (const float*)d_in[26 + dir];
        A.out[dir]  = (float*)d_out + (size_t)dir * NELT;
    }
    fused<<<dim3(1024, 2), 256, 0, stream>>>(A);
}

// Round 5
// 535.470 us; speedup vs baseline: 1.2329x; 1.0502x over previous
//
#include <hip/hip_runtime.h>

typedef short short8 __attribute__((ext_vector_type(8)));
typedef float f32x4 __attribute__((ext_vector_type(4)));

#define NELT 16777216  // B*S*C*D per tensor

__device__ __forceinline__ float b2f(unsigned short u) {
    return __uint_as_float(((unsigned)u) << 16);
}
__device__ __forceinline__ unsigned short f2b(float f) {
    unsigned u = __float_as_uint(f);
    u += 0x7FFF + ((u >> 16) & 1);   // RTN-even
    return (unsigned short)(u >> 16);
}
// Markidis split: f ~= b2f(hi) + b2f(lo)
__device__ __forceinline__ void split2(float f, unsigned short& hi, unsigned short& lo) {
    unsigned short h = f2b(f);
    hi = h;
    lo = f2b(f - b2f(h));
}
// row r of the (BC*S, D) flattened view -> flat offset into x (B,S,C,D)
__device__ __forceinline__ int xrow_off(int r) {
    int n = r >> 6, s = r & 63;
    int b = n >> 7, c = n & 127;
    return (((b << 6) + s) * 128 + c) << 8;
}
// XOR-swizzled LDS element offset, 64x256 bf16 tile, 8-elem chunks.
__device__ __forceinline__ int sw256(int row, int k) {
    return row * 256 + ((((k >> 3) ^ (row & 7)) << 3) | (k & 7));
}
// linearized B-fragment offset (in shorts): [nt][kk][ct][lq][lm][hi8|lo8]
__device__ __forceinline__ int boff(int nt, int kk, int ct, int lq, int lm) {
    return ((((nt * 8 + kk) * 4 + ct) * 4 + lq) * 16 + lm) * 16;
}

// ---- weight pre-linearization into MFMA B-fragment order (both dirs) ----
struct WArgs {
    const float* Wq[2]; const float* Wk[2]; const float* Wv[2]; const float* Wo[2];
    unsigned short* Bqkv[2]; unsigned short* Bo[2];
};
__global__ __launch_bounds__(256) void w_prep(WArgs A)
{
    const int dir = blockIdx.y;
    const int tid = blockIdx.x * 256 + threadIdx.x;
    const int lm = tid & 15, lq = (tid >> 4) & 3, ct = (tid >> 6) & 3;
    const int kk = (tid >> 8) & 7, nt = tid >> 11;
    const int c = ct * 16 + lm;
    {
        const float* W; int ldw, col;
        if (nt < 4)      { W = A.Wq[dir]; ldw = 256; col = nt * 64 + c; }
        else if (nt < 6) { W = A.Wk[dir]; ldw = 128; col = (nt - 4) * 64 + c; }
        else             { W = A.Wv[dir]; ldw = 128; col = (nt - 6) * 64 + c; }
        short8 h8, l8;
        #pragma unroll
        for (int j = 0; j < 8; ++j) {
            int k = kk * 32 + lq * 8 + j;
            unsigned short h, l;
            split2(W[k * ldw + col], h, l);
            h8[j] = (short)h; l8[j] = (short)l;
        }
        int off = boff(nt, kk, ct, lq, lm);
        *(short8*)&A.Bqkv[dir][off] = h8;
        *(short8*)&A.Bqkv[dir][off + 8] = l8;
    }
    if (nt < 4) {
        int col = nt * 64 + c;
        short8 h8, l8;
        #pragma unroll
        for (int j = 0; j < 8; ++j) {
            int k = kk * 32 + lq * 8 + j;
            unsigned short h, l;
            split2(A.Wo[dir][k * 256 + col], h, l);
            h8[j] = (short)h; l8[j] = (short)l;
        }
        int off = boff(nt, kk, ct, lq, lm);
        *(short8*)&A.Bo[dir][off] = h8;
        *(short8*)&A.Bo[dir][off + 8] = l8;
    }
}

struct FusedArgs {
    const float* xq[2];   const float* xkv[2];
    const float* gq[2];   const float* btq[2];
    const float* gkv[2];  const float* btkv[2];
    const unsigned short* Bqkv[2];
    const unsigned short* Bow[2];
    const float* bq[2];   const float* bk[2];
    const float* bv[2];   const float* bo[2];
    const float* gate[2];
    float* out[2];
};

// ======================= fully-fused per-sequence kernel ==================
// 512 threads (8 waves), grid (1024, 2). Each wave owns a 32-col slab:
//   Q/O GEMM: wave w -> cols w*32..+31.  KV GEMM: waves 0-3 K, 4-7 V.
//   Attention: wave w -> q-head w (KV head w>>1). One head per wave.
// Halved per-wave accumulators (32 f32) keep VGPR+AGPR <= 128 so
// launch_bounds(512,4) -> 4 waves/SIMD = 2 blocks/CU (R4 post-mortem:
// AGPR accumulators count against the unified file; 64-col slabs gave
// ~256 total regs -> stuck at 2 waves/SIMD).
// LDS 64 KiB, time-multiplexed:
//   Ah/Al [0,64K) staging  |  K/V slots [0,39K) between KV GEMM and stage xq
//   Qs [0,41K) + P strips [40K,59K) after Q GEMM (all wave-private).
__global__ __launch_bounds__(512, 4) void fused(FusedArgs P_)
{
    __shared__ char SM[65536];
    unsigned short* Ah = (unsigned short*)SM;              // [64*256]
    unsigned short* Al = (unsigned short*)(SM + 32768);
    const int dir = blockIdx.y;
    const int n = blockIdx.x, t = threadIdx.x;
    const int r0 = n * 64;
    const int w = t >> 6, l = t & 63, lm = l & 15, lq = l >> 4;

    const float* xq  = P_.xq[dir];
    const float* xkv = P_.xkv[dir];
    const unsigned short* Bq  = P_.Bqkv[dir];
    const unsigned short* BoW = P_.Bow[dir];

    // ------- staging: LN + split2 of all 64 rows (8 waves x 8 iters) -------
    auto stage = [&](const float* X, const float4& gv, const float4& b4) {
        float4 xv[8];
        #pragma unroll
        for (int it = 0; it < 8; ++it)
            xv[it] = *(const float4*)(X + xrow_off(r0 + it * 8 + w) + l * 4);
        #pragma unroll
        for (int it = 0; it < 8; ++it) {
            int row = it * 8 + w;
            float4 x4 = xv[it];
            float s1 = x4.x + x4.y + x4.z + x4.w;
            float s2 = x4.x * x4.x + x4.y * x4.y + x4.z * x4.z + x4.w * x4.w;
            #pragma unroll
            for (int m = 1; m < 64; m <<= 1) {
                s1 += __shfl_xor(s1, m);
                s2 += __shfl_xor(s2, m);
            }
            float mu = s1 * (1.f / 256.f);
            float rstd = rsqrtf(s2 * (1.f / 256.f) - mu * mu + 1e-5f);
            float v0 = (x4.x - mu) * rstd * gv.x + b4.x;
            float v1 = (x4.y - mu) * rstd * gv.y + b4.y;
            float v2 = (x4.z - mu) * rstd * gv.z + b4.z;
            float v3 = (x4.w - mu) * rstd * gv.w + b4.w;
            ushort4 oh, ol;
            split2(v0, oh.x, ol.x); split2(v1, oh.y, ol.y);
            split2(v2, oh.z, ol.z); split2(v3, oh.w, ol.w);
            *(ushort4*)&Ah[sw256(row, l * 4)] = oh;
            *(ushort4*)&Al[sw256(row, l * 4)] = ol;
        }
    };
    // one 32-col GEMM slab: acc[m][i] over cols nt*64 + (ct0+i)*16 + lm
    auto gemm32 = [&](f32x4 (&acc)[4][2], const unsigned short* B,
                      int nt, int ct0) {
        #pragma unroll
        for (int kk = 0; kk < 8; ++kk) {
            int k0 = kk * 32 + lq * 8;
            short8 ah[4], al[4];
            #pragma unroll
            for (int m = 0; m < 4; ++m) {
                ah[m] = *(const short8*)&Ah[sw256(m * 16 + lm, k0)];
                al[m] = *(const short8*)&Al[sw256(m * 16 + lm, k0)];
            }
            #pragma unroll
            for (int i = 0; i < 2; ++i) {
                int off = boff(nt, kk, ct0 + i, lq, lm);
                short8 bh = *(const short8*)&B[off];
                short8 bl = *(const short8*)&B[off + 8];
                #pragma unroll
                for (int m = 0; m < 4; ++m) {
                    acc[m][i] = __builtin_amdgcn_mfma_f32_16x16x32_bf16(ah[m], bh, acc[m][i], 0, 0, 0);
                    acc[m][i] = __builtin_amdgcn_mfma_f32_16x16x32_bf16(al[m], bh, acc[m][i], 0, 0, 0);
                    acc[m][i] = __builtin_amdgcn_mfma_f32_16x16x32_bf16(ah[m], bl, acc[m][i], 0, 0, 0);
                }
            }
        }
    };

    // ============ phase 1: stage LN(xkv); phase 2: K or V slab ============
    {
        const float4 gv = *(const float4*)(P_.gkv[dir] + l * 4);
        const float4 b4 = *(const float4*)(P_.btkv[dir] + l * 4);
        stage(xkv, gv, b4);
    }
    __syncthreads();
    {
        f32x4 acc[4][2] = {};
        const int wk = w & 3;                      // slab index within K or V
        const bool isV = w >= 4;
        const int nt = (isV ? 6 : 4) + (wk >> 1);
        const int ct0 = (wk & 1) * 2;
        gemm32(acc, Bq, nt, ct0);
        __syncthreads();   // done reading Ah/Al; slots may be written
        // repack: K-waves -> Kslot[wk] [64 keys][40]; V-waves -> Vslot[wk] V^T [32][72]
        const float* bias = isV ? P_.bv[dir] : P_.bk[dir];
        float bi0 = bias[wk * 32 + lm], bi1 = bias[wk * 32 + 16 + lm];
        if (!isV) {
            unsigned short* Ks = (unsigned short*)(SM + wk * 5120);
            #pragma unroll
            for (int m = 0; m < 4; ++m)
                #pragma unroll
                for (int rg = 0; rg < 4; ++rg) {
                    int key = m * 16 + lq * 4 + rg;
                    Ks[key * 40 + lm]      = f2b(acc[m][0][rg] + bi0);
                    Ks[key * 40 + 16 + lm] = f2b(acc[m][1][rg] + bi1);
                }
        } else {
            unsigned short* Vs = (unsigned short*)(SM + 20480 + wk * 4608);
            #pragma unroll
            for (int m = 0; m < 4; ++m)
                #pragma unroll
                for (int rg = 0; rg < 4; ++rg) {
                    int key = m * 16 + lq * 4 + rg;
                    Vs[lm * 72 + key]        = f2b(acc[m][0][rg] + bi0);
                    Vs[(16 + lm) * 72 + key] = f2b(acc[m][1][rg] + bi1);
                }
        }
    }
    __syncthreads();   // slots complete; all waves read their head's K/V

    const int g2 = w >> 1;                          // KV head for q-head w
    short8 kf[4];
    {
        const unsigned short* Ks = (const unsigned short*)(SM + g2 * 5120);
        #pragma unroll
        for (int nt = 0; nt < 4; ++nt)
            kf[nt] = *(const short8*)&Ks[(nt * 16 + lm) * 40 + lq * 8];
    }
    short8 vb[2][2];
    {
        const unsigned short* Vs = (const unsigned short*)(SM + 20480 + g2 * 4608);
        #pragma unroll
        for (int kt = 0; kt < 2; ++kt) {
            vb[kt][0] = *(const short8*)&Vs[lm * 72 + kt * 32 + lq * 8];
            vb[kt][1] = *(const short8*)&Vs[(16 + lm) * 72 + kt * 32 + lq * 8];
        }
    }
    __syncthreads();   // kf/vb in regs; LDS free for xq staging

    // ============ phase 3: stage LN(xq); phase 4: Q slab ============
    {
        const float4 gv = *(const float4*)(P_.gq[dir] + l * 4);
        const float4 b4 = *(const float4*)(P_.btq[dir] + l * 4);
        stage(xq, gv, b4);
    }
    __syncthreads();
    f32x4 o[4][2] = {};
    {
        f32x4 qacc[4][2] = {};
        gemm32(qacc, Bq, w >> 1, (w & 1) * 2);
        __syncthreads();   // done reading Ah/Al; Qs slots may be written
        // Q repack (wave-private): Qs [64 rows][40]
        unsigned short* Qs = (unsigned short*)(SM + w * 5120);
        float bq0 = P_.bq[dir][w * 32 + lm], bq1 = P_.bq[dir][w * 32 + 16 + lm];
        #pragma unroll
        for (int m = 0; m < 4; ++m)
            #pragma unroll
            for (int rg = 0; rg < 4; ++rg) {
                int row = (m * 16 + lq * 4 + rg) * 40;
                Qs[row + lm]      = f2b(qacc[m][0][rg] + bq0);
                Qs[row + 16 + lm] = f2b(qacc[m][1][rg] + bq1);
            }
        // ====== attention: head h = w, fully wave-synchronous ======
        unsigned short* Ps = (unsigned short*)(SM + 40960 + w * 2304); // [16][72]
        const float scale = 0.17677669529663687f;    // 1/sqrt(32)
        #pragma unroll 1
        for (int mt = 0; mt < 4; ++mt) {
            short8 qf = *(const short8*)&Qs[(mt * 16 + lm) * 40 + lq * 8];
            f32x4 s[4];
            #pragma unroll
            for (int nt = 0; nt < 4; ++nt) {
                f32x4 z = {0, 0, 0, 0};
                s[nt] = __builtin_amdgcn_mfma_f32_16x16x32_bf16(qf, kf[nt], z, 0, 0, 0);
            }
            #pragma unroll
            for (int rg = 0; rg < 4; ++rg) {
                float mx = fmaxf(fmaxf(s[0][rg], s[1][rg]),
                                 fmaxf(s[2][rg], s[3][rg]));
                #pragma unroll
                for (int msk = 1; msk < 16; msk <<= 1)
                    mx = fmaxf(mx, __shfl_xor(mx, msk));
                float p0 = __expf((s[0][rg] - mx) * scale);
                float p1 = __expf((s[1][rg] - mx) * scale);
                float p2 = __expf((s[2][rg] - mx) * scale);
                float p3 = __expf((s[3][rg] - mx) * scale);
                float sum = p0 + p1 + p2 + p3;
                #pragma unroll
                for (int msk = 1; msk < 16; msk <<= 1)
                    sum += __shfl_xor(sum, msk);
                float inv = 1.f / sum;
                int rowb = (lq * 4 + rg) * 72 + lm;
                Ps[rowb + 0]  = f2b(p0 * inv);
                Ps[rowb + 16] = f2b(p1 * inv);
                Ps[rowb + 32] = f2b(p2 * inv);
                Ps[rowb + 48] = f2b(p3 * inv);
            }
            #pragma unroll
            for (int kt = 0; kt < 2; ++kt) {
                short8 pa = *(const short8*)&Ps[lm * 72 + kt * 32 + lq * 8];
                o[mt][0] = __builtin_amdgcn_mfma_f32_16x16x32_bf16(pa, vb[kt][0], o[mt][0], 0, 0, 0);
                o[mt][1] = __builtin_amdgcn_mfma_f32_16x16x32_bf16(pa, vb[kt][1], o[mt][1], 0, 0, 0);
            }
        }
    }
    __syncthreads();   // all waves done with slots; LDS free for attn-out

    // ====== attn-out -> Ah/Al (split bf16, swizzled); O slab; epilogue =====
    #pragma unroll
    for (int m = 0; m < 4; ++m)
        #pragma unroll
        for (int n2 = 0; n2 < 2; ++n2)
            #pragma unroll
            for (int rg = 0; rg < 4; ++rg) {
                int row = m * 16 + lq * 4 + rg;
                int col = w * 32 + n2 * 16 + lm;
                unsigned short h_, l_;
                split2(o[m][n2][rg], h_, l_);
                int sw = sw256(row, col);
                Ah[sw] = h_;
                Al[sw] = l_;
            }
    __syncthreads();
    {
        f32x4 acc[4][2] = {};
        gemm32(acc, BoW, w >> 1, (w & 1) * 2);
        float sig = 1.f / (1.f + __expf(-P_.gate[dir][0]));
        const float* Xres = xq;
        float* Out = P_.out[dir];
        #pragma unroll
        for (int i = 0; i < 2; ++i) {
            int col = w * 32 + i * 16 + lm;
            float bias = P_.bo[dir][col];
            #pragma unroll
            for (int m = 0; m < 4; ++m)
                #pragma unroll
                for (int rg = 0; rg < 4; ++rg) {
                    int row = m * 16 + lq * 4 + rg;
                    int oidx = xrow_off(r0 + row) + col;
                    Out[oidx] = Xres[oidx] + sig * (acc[m][i][rg] + bias);
                }
        }
    }
}

extern "C" void kernel_launch(void* const* d_in, const int* in_sizes, int n_in,
                              void* d_out, int out_size, void* d_ws, size_t ws_size,
                              hipStream_t stream) {
    const float* x_spec = (const float*)d_in[0];
    const float* x_spat = (const float*)d_in[1];
    const float* ln_g[4] = {(const float*)d_in[2], (const float*)d_in[4],
                            (const float*)d_in[6], (const float*)d_in[8]};
    const float* ln_b[4] = {(const float*)d_in[3], (const float*)d_in[5],
                            (const float*)d_in[7], (const float*)d_in[9]};
    char* ws = (char*)d_ws;
    unsigned short* Bqkv[2] = {(unsigned short*)ws,
                               (unsigned short*)(ws + (512 << 10))};     // 2 x 512 KiB
    unsigned short* BoL[2]  = {(unsigned short*)(ws + (1024 << 10)),
                               (unsigned short*)(ws + (1280 << 10))};    // 2 x 256 KiB

    WArgs WA;
    for (int dir = 0; dir < 2; ++dir) {
        int base = 10 + dir * 8;
        WA.Wq[dir] = (const float*)d_in[base + 0];
        WA.Wk[dir] = (const float*)d_in[base + 2];
        WA.Wv[dir] = (const float*)d_in[base + 4];
        WA.Wo[dir] = (const float*)d_in[base + 6];
        WA.Bqkv[dir] = Bqkv[dir];
        WA.Bo[dir]   = BoL[dir];
    }
    w_prep<<<dim3(64, 2), 256, 0, stream>>>(WA);

    FusedArgs A;
    for (int dir = 0; dir < 2; ++dir) {
        int base = 10 + dir * 8;
        A.xq[dir]   = dir == 0 ? x_spec : x_spat;
        A.xkv[dir]  = dir == 0 ? x_spat : x_spec;
        A.gq[dir]   = dir == 0 ? ln_g[0] : ln_g[2];
        A.btq[dir]  = dir == 0 ? ln_b[0] : ln_b[2];
        A.gkv[dir]  = dir == 0 ? ln_g[3] : ln_g[1];
        A.btkv[dir] = dir == 0 ? ln_b[3] : ln_b[1];
        A.Bqkv[dir] = Bqkv[dir];
        A.Bow[dir]  = BoL[dir];
        A.bq[dir]   = (const float*)d_in[base + 1];
        A.bk[dir]   = (const float*)d_in[base + 3];
        A.bv[dir]   = (const float*)d_in[base + 5];
        A.bo[dir]   = (const float*)d_in[base + 7];
        A.gate[dir] = (const float*)d_in[26 + dir];
        A.out[dir]  = (float*)d_out + (size_t)dir * NELT;
    }
    fused<<<dim3(1024, 2), 512, 0, stream>>>(A);
}

// Round 6
// 507.444 us; speedup vs baseline: 1.3010x; 1.0552x over previous
//
#include <hip/hip_runtime.h>

typedef short short8 __attribute__((ext_vector_type(8)));
typedef float f32x4 __attribute__((ext_vector_type(4)));

#define NELT 16777216  // B*S*C*D per tensor

__device__ __forceinline__ float b2f(unsigned short u) {
    return __uint_as_float(((unsigned)u) << 16);
}
__device__ __forceinline__ unsigned short f2b(float f) {
    unsigned u = __float_as_uint(f);
    u += 0x7FFF + ((u >> 16) & 1);   // RTN-even
    return (unsigned short)(u >> 16);
}
// Markidis split: f ~= b2f(hi) + b2f(lo)
__device__ __forceinline__ void split2(float f, unsigned short& hi, unsigned short& lo) {
    unsigned short h = f2b(f);
    hi = h;
    lo = f2b(f - b2f(h));
}
// row r of the (BC*S, D) flattened view -> flat offset into x (B,S,C,D)
__device__ __forceinline__ int xrow_off(int r) {
    int n = r >> 6, s = r & 63;
    int b = n >> 7, c = n & 127;
    return (((b << 6) + s) * 128 + c) << 8;
}
// XOR-swizzled LDS element offset, 64x256 bf16 tile, 8-elem chunks.
__device__ __forceinline__ int sw256(int row, int k) {
    return row * 256 + ((((k >> 3) ^ (row & 7)) << 3) | (k & 7));
}
// linearized B-fragment offset (in shorts): [nt][kk][ct][lq][lm][hi8|lo8]
__device__ __forceinline__ int boff(int nt, int kk, int ct, int lq, int lm) {
    return ((((nt * 8 + kk) * 4 + ct) * 4 + lq) * 16 + lm) * 16;
}

// ---- weight pre-linearization into MFMA B-fragment order (both dirs) ----
struct WArgs {
    const float* Wq[2]; const float* Wk[2]; const float* Wv[2]; const float* Wo[2];
    unsigned short* Bqkv[2]; unsigned short* Bo[2];
};
__global__ __launch_bounds__(256) void w_prep(WArgs A)
{
    const int dir = blockIdx.y;
    const int tid = blockIdx.x * 256 + threadIdx.x;
    const int lm = tid & 15, lq = (tid >> 4) & 3, ct = (tid >> 6) & 3;
    const int kk = (tid >> 8) & 7, nt = tid >> 11;
    const int c = ct * 16 + lm;
    {
        const float* W; int ldw, col;
        if (nt < 4)      { W = A.Wq[dir]; ldw = 256; col = nt * 64 + c; }
        else if (nt < 6) { W = A.Wk[dir]; ldw = 128; col = (nt - 4) * 64 + c; }
        else             { W = A.Wv[dir]; ldw = 128; col = (nt - 6) * 64 + c; }
        short8 h8, l8;
        #pragma unroll
        for (int j = 0; j < 8; ++j) {
            int k = kk * 32 + lq * 8 + j;
            unsigned short h, l;
            split2(W[k * ldw + col], h, l);
            h8[j] = (short)h; l8[j] = (short)l;
        }
        int off = boff(nt, kk, ct, lq, lm);
        *(short8*)&A.Bqkv[dir][off] = h8;
        *(short8*)&A.Bqkv[dir][off + 8] = l8;
    }
    if (nt < 4) {
        int col = nt * 64 + c;
        short8 h8, l8;
        #pragma unroll
        for (int j = 0; j < 8; ++j) {
            int k = kk * 32 + lq * 8 + j;
            unsigned short h, l;
            split2(A.Wo[dir][k * 256 + col], h, l);
            h8[j] = (short)h; l8[j] = (short)l;
        }
        int off = boff(nt, kk, ct, lq, lm);
        *(short8*)&A.Bo[dir][off] = h8;
        *(short8*)&A.Bo[dir][off + 8] = l8;
    }
}

struct FusedArgs {
    const float* xq[2];   const float* xkv[2];
    const float* gq[2];   const float* btq[2];
    const float* gkv[2];  const float* btkv[2];
    const unsigned short* Bqkv[2];
    const unsigned short* Bow[2];
    const float* bq[2];   const float* bk[2];
    const float* bv[2];   const float* bo[2];
    const float* gate[2];
    float* out[2];
};

// ======================= fully-fused per-sequence kernel ==================
// 512 threads (8 waves), grid (1024, 2). Each wave owns a 32-col slab.
// launch_bounds(512,4): 4 waves/SIMD; allocator budget 128/wave split
// 64 arch-VGPR + 64 AGPR (R5 post-mortem). Per-wave ARCH-VGPR live state
// must fit 64 or it spills to scratch (R5: +330 MB HBM). Diet applied:
//   - gemm32 loads bh/bl[2] first then per-m ah/al (live A-frags 32->8)
//   - stage() runs in two 4-row batches (xv[4] not xv[8])
__global__ __launch_bounds__(512, 4) void fused(FusedArgs P_)
{
    __shared__ char SM[65536];
    unsigned short* Ah = (unsigned short*)SM;              // [64*256]
    unsigned short* Al = (unsigned short*)(SM + 32768);
    const int dir = blockIdx.y;
    const int n = blockIdx.x, t = threadIdx.x;
    const int r0 = n * 64;
    const int w = t >> 6, l = t & 63, lm = l & 15, lq = l >> 4;

    const float* xq  = P_.xq[dir];
    const float* xkv = P_.xkv[dir];
    const unsigned short* Bq  = P_.Bqkv[dir];
    const unsigned short* BoW = P_.Bow[dir];

    // ------- staging: LN + split2 of all 64 rows (8 waves x 8 rows) -------
    auto stage = [&](const float* X, const float4& gv, const float4& b4) {
        #pragma unroll
        for (int half = 0; half < 2; ++half) {
            float4 xv[4];
            #pragma unroll
            for (int it = 0; it < 4; ++it)
                xv[it] = *(const float4*)(X + xrow_off(r0 + (half * 4 + it) * 8 + w) + l * 4);
            #pragma unroll
            for (int it = 0; it < 4; ++it) {
                int row = (half * 4 + it) * 8 + w;
                float4 x4 = xv[it];
                float s1 = x4.x + x4.y + x4.z + x4.w;
                float s2 = x4.x * x4.x + x4.y * x4.y + x4.z * x4.z + x4.w * x4.w;
                #pragma unroll
                for (int m = 1; m < 64; m <<= 1) {
                    s1 += __shfl_xor(s1, m);
                    s2 += __shfl_xor(s2, m);
                }
                float mu = s1 * (1.f / 256.f);
                float rstd = rsqrtf(s2 * (1.f / 256.f) - mu * mu + 1e-5f);
                float v0 = (x4.x - mu) * rstd * gv.x + b4.x;
                float v1 = (x4.y - mu) * rstd * gv.y + b4.y;
                float v2 = (x4.z - mu) * rstd * gv.z + b4.z;
                float v3 = (x4.w - mu) * rstd * gv.w + b4.w;
                ushort4 oh, ol;
                split2(v0, oh.x, ol.x); split2(v1, oh.y, ol.y);
                split2(v2, oh.z, ol.z); split2(v3, oh.w, ol.w);
                *(ushort4*)&Ah[sw256(row, l * 4)] = oh;
                *(ushort4*)&Al[sw256(row, l * 4)] = ol;
            }
        }
    };
    // one 32-col GEMM slab: acc[m][i] over cols nt*64 + (ct0+i)*16 + lm.
    // B-frags (16 regs) held across the m-loop; A-frags (8 regs) per m.
    auto gemm32 = [&](f32x4 (&acc)[4][2], const unsigned short* B,
                      int nt, int ct0) {
        #pragma unroll
        for (int kk = 0; kk < 8; ++kk) {
            int k0 = kk * 32 + lq * 8;
            short8 bh[2], bl[2];
            #pragma unroll
            for (int i = 0; i < 2; ++i) {
                int off = boff(nt, kk, ct0 + i, lq, lm);
                bh[i] = *(const short8*)&B[off];
                bl[i] = *(const short8*)&B[off + 8];
            }
            #pragma unroll
            for (int m = 0; m < 4; ++m) {
                short8 ah = *(const short8*)&Ah[sw256(m * 16 + lm, k0)];
                short8 al = *(const short8*)&Al[sw256(m * 16 + lm, k0)];
                #pragma unroll
                for (int i = 0; i < 2; ++i) {
                    acc[m][i] = __builtin_amdgcn_mfma_f32_16x16x32_bf16(ah, bh[i], acc[m][i], 0, 0, 0);
                    acc[m][i] = __builtin_amdgcn_mfma_f32_16x16x32_bf16(al, bh[i], acc[m][i], 0, 0, 0);
                    acc[m][i] = __builtin_amdgcn_mfma_f32_16x16x32_bf16(ah, bl[i], acc[m][i], 0, 0, 0);
                }
            }
        }
    };

    // ============ phase 1: stage LN(xkv); phase 2: K or V slab ============
    {
        const float4 gv = *(const float4*)(P_.gkv[dir] + l * 4);
        const float4 b4 = *(const float4*)(P_.btkv[dir] + l * 4);
        stage(xkv, gv, b4);
    }
    __syncthreads();
    {
        f32x4 acc[4][2] = {};
        const int wk = w & 3;                      // slab index within K or V
        const bool isV = w >= 4;
        const int nt = (isV ? 6 : 4) + (wk >> 1);
        const int ct0 = (wk & 1) * 2;
        gemm32(acc, Bq, nt, ct0);
        __syncthreads();   // done reading Ah/Al; slots may be written
        // repack: K-waves -> Kslot[wk] [64 keys][40]; V-waves -> Vslot[wk] V^T [32][72]
        const float* bias = isV ? P_.bv[dir] : P_.bk[dir];
        float bi0 = bias[wk * 32 + lm], bi1 = bias[wk * 32 + 16 + lm];
        if (!isV) {
            unsigned short* Ks = (unsigned short*)(SM + wk * 5120);
            #pragma unroll
            for (int m = 0; m < 4; ++m)
                #pragma unroll
                for (int rg = 0; rg < 4; ++rg) {
                    int key = m * 16 + lq * 4 + rg;
                    Ks[key * 40 + lm]      = f2b(acc[m][0][rg] + bi0);
                    Ks[key * 40 + 16 + lm] = f2b(acc[m][1][rg] + bi1);
                }
        } else {
            unsigned short* Vs = (unsigned short*)(SM + 20480 + wk * 4608);
            #pragma unroll
            for (int m = 0; m < 4; ++m)
                #pragma unroll
                for (int rg = 0; rg < 4; ++rg) {
                    int key = m * 16 + lq * 4 + rg;
                    Vs[lm * 72 + key]        = f2b(acc[m][0][rg] + bi0);
                    Vs[(16 + lm) * 72 + key] = f2b(acc[m][1][rg] + bi1);
                }
        }
    }
    __syncthreads();   // slots complete; all waves read their head's K/V

    const int g2 = w >> 1;                          // KV head for q-head w
    short8 kf[4];
    {
        const unsigned short* Ks = (const unsigned short*)(SM + g2 * 5120);
        #pragma unroll
        for (int nt = 0; nt < 4; ++nt)
            kf[nt] = *(const short8*)&Ks[(nt * 16 + lm) * 40 + lq * 8];
    }
    short8 vb[2][2];
    {
        const unsigned short* Vs = (const unsigned short*)(SM + 20480 + g2 * 4608);
        #pragma unroll
        for (int kt = 0; kt < 2; ++kt) {
            vb[kt][0] = *(const short8*)&Vs[lm * 72 + kt * 32 + lq * 8];
            vb[kt][1] = *(const short8*)&Vs[(16 + lm) * 72 + kt * 32 + lq * 8];
        }
    }
    __syncthreads();   // kf/vb in regs; LDS free for xq staging

    // ============ phase 3: stage LN(xq); phase 4: Q slab ============
    {
        const float4 gv = *(const float4*)(P_.gq[dir] + l * 4);
        const float4 b4 = *(const float4*)(P_.btq[dir] + l * 4);
        stage(xq, gv, b4);
    }
    __syncthreads();
    f32x4 o[4][2] = {};
    {
        f32x4 qacc[4][2] = {};
        gemm32(qacc, Bq, w >> 1, (w & 1) * 2);
        __syncthreads();   // done reading Ah/Al; Qs slots may be written
        // Q repack (wave-private): Qs [64 rows][40]
        unsigned short* Qs = (unsigned short*)(SM + w * 5120);
        float bq0 = P_.bq[dir][w * 32 + lm], bq1 = P_.bq[dir][w * 32 + 16 + lm];
        #pragma unroll
        for (int m = 0; m < 4; ++m)
            #pragma unroll
            for (int rg = 0; rg < 4; ++rg) {
                int row = (m * 16 + lq * 4 + rg) * 40;
                Qs[row + lm]      = f2b(qacc[m][0][rg] + bq0);
                Qs[row + 16 + lm] = f2b(qacc[m][1][rg] + bq1);
            }
        // ====== attention: head h = w, fully wave-synchronous ======
        unsigned short* Ps = (unsigned short*)(SM + 40960 + w * 2304); // [16][72]
        const float scale = 0.17677669529663687f;    // 1/sqrt(32)
        #pragma unroll 1
        for (int mt = 0; mt < 4; ++mt) {
            short8 qf = *(const short8*)&Qs[(mt * 16 + lm) * 40 + lq * 8];
            f32x4 s[4];
            #pragma unroll
            for (int nt = 0; nt < 4; ++nt) {
                f32x4 z = {0, 0, 0, 0};
                s[nt] = __builtin_amdgcn_mfma_f32_16x16x32_bf16(qf, kf[nt], z, 0, 0, 0);
            }
            #pragma unroll
            for (int rg = 0; rg < 4; ++rg) {
                float mx = fmaxf(fmaxf(s[0][rg], s[1][rg]),
                                 fmaxf(s[2][rg], s[3][rg]));
                #pragma unroll
                for (int msk = 1; msk < 16; msk <<= 1)
                    mx = fmaxf(mx, __shfl_xor(mx, msk));
                float p0 = __expf((s[0][rg] - mx) * scale);
                float p1 = __expf((s[1][rg] - mx) * scale);
                float p2 = __expf((s[2][rg] - mx) * scale);
                float p3 = __expf((s[3][rg] - mx) * scale);
                float sum = p0 + p1 + p2 + p3;
                #pragma unroll
                for (int msk = 1; msk < 16; msk <<= 1)
                    sum += __shfl_xor(sum, msk);
                float inv = 1.f / sum;
                int rowb = (lq * 4 + rg) * 72 + lm;
                Ps[rowb + 0]  = f2b(p0 * inv);
                Ps[rowb + 16] = f2b(p1 * inv);
                Ps[rowb + 32] = f2b(p2 * inv);
                Ps[rowb + 48] = f2b(p3 * inv);
            }
            #pragma unroll
            for (int kt = 0; kt < 2; ++kt) {
                short8 pa = *(const short8*)&Ps[lm * 72 + kt * 32 + lq * 8];
                o[mt][0] = __builtin_amdgcn_mfma_f32_16x16x32_bf16(pa, vb[kt][0], o[mt][0], 0, 0, 0);
                o[mt][1] = __builtin_amdgcn_mfma_f32_16x16x32_bf16(pa, vb[kt][1], o[mt][1], 0, 0, 0);
            }
        }
    }
    __syncthreads();   // all waves done with slots; LDS free for attn-out

    // ====== attn-out -> Ah/Al (split bf16, swizzled); O slab; epilogue =====
    #pragma unroll
    for (int m = 0; m < 4; ++m)
        #pragma unroll
        for (int n2 = 0; n2 < 2; ++n2)
            #pragma unroll
            for (int rg = 0; rg < 4; ++rg) {
                int row = m * 16 + lq * 4 + rg;
                int col = w * 32 + n2 * 16 + lm;
                unsigned short h_, l_;
                split2(o[m][n2][rg], h_, l_);
                int sw = sw256(row, col);
                Ah[sw] = h_;
                Al[sw] = l_;
            }
    __syncthreads();
    {
        f32x4 acc[4][2] = {};
        gemm32(acc, BoW, w >> 1, (w & 1) * 2);
        float sig = 1.f / (1.f + __expf(-P_.gate[dir][0]));
        const float* Xres = xq;
        float* Out = P_.out[dir];
        #pragma unroll
        for (int i = 0; i < 2; ++i) {
            int col = w * 32 + i * 16 + lm;
            float bias = P_.bo[dir][col];
            #pragma unroll
            for (int m = 0; m < 4; ++m)
                #pragma unroll
                for (int rg = 0; rg < 4; ++rg) {
                    int row = m * 16 + lq * 4 + rg;
                    int oidx = xrow_off(r0 + row) + col;
                    Out[oidx] = Xres[oidx] + sig * (acc[m][i][rg] + bias);
                }
        }
    }
}

extern "C" void kernel_launch(void* const* d_in, const int* in_sizes, int n_in,
                              void* d_out, int out_size, void* d_ws, size_t ws_size,
                              hipStream_t stream) {
    const float* x_spec = (const float*)d_in[0];
    const float* x_spat = (const float*)d_in[1];
    const float* ln_g[4] = {(const float*)d_in[2], (const float*)d_in[4],
                            (const float*)d_in[6], (const float*)d_in[8]};
    const float* ln_b[4] = {(const float*)d_in[3], (const float*)d_in[5],
                            (const float*)d_in[7], (const float*)d_in[9]};
    char* ws = (char*)d_ws;
    unsigned short* Bqkv[2] = {(unsigned short*)ws,
                               (unsigned short*)(ws + (512 << 10))};     // 2 x 512 KiB
    unsigned short* BoL[2]  = {(unsigned short*)(ws + (1024 << 10)),
                               (unsigned short*)(ws + (1280 << 10))};    // 2 x 256 KiB

    WArgs WA;
    for (int dir = 0; dir < 2; ++dir) {
        int base = 10 + dir * 8;
        WA.Wq[dir] = (const float*)d_in[base + 0];
        WA.Wk[dir] = (const float*)d_in[base + 2];
        WA.Wv[dir] = (const float*)d_in[base + 4];
        WA.Wo[dir] = (const float*)d_in[base + 6];
        WA.Bqkv[dir] = Bqkv[dir];
        WA.Bo[dir]   = BoL[dir];
    }
    w_prep<<<dim3(64, 2), 256, 0, stream>>>(WA);

    FusedArgs A;
    for (int dir = 0; dir < 2; ++dir) {
        int base = 10 + dir * 8;
        A.xq[dir]   = dir == 0 ? x_spec : x_spat;
        A.xkv[dir]  = dir == 0 ? x_spat : x_spec;
        A.gq[dir]   = dir == 0 ? ln_g[0] : ln_g[2];
        A.btq[dir]  = dir == 0 ? ln_b[0] : ln_b[2];
        A.gkv[dir]  = dir == 0 ? ln_g[3] : ln_g[1];
        A.btkv[dir] = dir == 0 ? ln_b[3] : ln_b[1];
        A.Bqkv[dir] = Bqkv[dir];
        A.Bow[dir]  = BoL[dir];
        A.bq[dir]   = (const float*)d_in[base + 1];
        A.bk[dir]   = (const float*)d_in[base + 3];
        A.bv[dir]   = (const float*)d_in[base + 5];
        A.bo[dir]   = (const float*)d_in[base + 7];
        A.gate[dir] = (const float*)d_in[26 + dir];
        A.out[dir]  = (float*)d_out + (size_t)dir * NELT;
    }
    fused<<<dim3(1024, 2), 512, 0, stream>>>(A);
}

// Round 7
// 473.257 us; speedup vs baseline: 1.3949x; 1.0722x over previous
//
#include <hip/hip_runtime.h>

typedef short short8 __attribute__((ext_vector_type(8)));
typedef float f32x4 __attribute__((ext_vector_type(4)));

#define NELT 16777216  // B*S*C*D per tensor

__device__ __forceinline__ float b2f(unsigned short u) {
    return __uint_as_float(((unsigned)u) << 16);
}
__device__ __forceinline__ unsigned short f2b(float f) {
    unsigned u = __float_as_uint(f);
    u += 0x7FFF + ((u >> 16) & 1);   // RTN-even
    return (unsigned short)(u >> 16);
}
// Markidis split: f ~= b2f(hi) + b2f(lo)
__device__ __forceinline__ void split2(float f, unsigned short& hi, unsigned short& lo) {
    unsigned short h = f2b(f);
    hi = h;
    lo = f2b(f - b2f(h));
}
// row r of the (BC*S, D) flattened view -> flat offset into x (B,S,C,D)
__device__ __forceinline__ int xrow_off(int r) {
    int n = r >> 6, s = r & 63;
    int b = n >> 7, c = n & 127;
    return (((b << 6) + s) * 128 + c) << 8;
}
// XOR-swizzled LDS element offset, 32x256 bf16 half-tile, 8-elem chunks.
__device__ __forceinline__ int sw256(int row, int k) {
    return row * 256 + ((((k >> 3) ^ (row & 7)) << 3) | (k & 7));
}
// linearized B-fragment offset (in shorts): [nt][kk][ct][lq][lm][hi8|lo8]
__device__ __forceinline__ int boff(int nt, int kk, int ct, int lq, int lm) {
    return ((((nt * 8 + kk) * 4 + ct) * 4 + lq) * 16 + lm) * 16;
}

// ---- weight pre-linearization into MFMA B-fragment order (both dirs) ----
struct WArgs {
    const float* Wq[2]; const float* Wk[2]; const float* Wv[2]; const float* Wo[2];
    unsigned short* Bqkv[2]; unsigned short* Bo[2];
};
__global__ __launch_bounds__(256) void w_prep(WArgs A)
{
    const int dir = blockIdx.y;
    const int tid = blockIdx.x * 256 + threadIdx.x;
    const int lm = tid & 15, lq = (tid >> 4) & 3, ct = (tid >> 6) & 3;
    const int kk = (tid >> 8) & 7, nt = tid >> 11;
    const int c = ct * 16 + lm;
    {
        const float* W; int ldw, col;
        if (nt < 4)      { W = A.Wq[dir]; ldw = 256; col = nt * 64 + c; }
        else if (nt < 6) { W = A.Wk[dir]; ldw = 128; col = (nt - 4) * 64 + c; }
        else             { W = A.Wv[dir]; ldw = 128; col = (nt - 6) * 64 + c; }
        short8 h8, l8;
        #pragma unroll
        for (int j = 0; j < 8; ++j) {
            int k = kk * 32 + lq * 8 + j;
            unsigned short h, l;
            split2(W[k * ldw + col], h, l);
            h8[j] = (short)h; l8[j] = (short)l;
        }
        int off = boff(nt, kk, ct, lq, lm);
        *(short8*)&A.Bqkv[dir][off] = h8;
        *(short8*)&A.Bqkv[dir][off + 8] = l8;
    }
    if (nt < 4) {
        int col = nt * 64 + c;
        short8 h8, l8;
        #pragma unroll
        for (int j = 0; j < 8; ++j) {
            int k = kk * 32 + lq * 8 + j;
            unsigned short h, l;
            split2(A.Wo[dir][k * 256 + col], h, l);
            h8[j] = (short)h; l8[j] = (short)l;
        }
        int off = boff(nt, kk, ct, lq, lm);
        *(short8*)&A.Bo[dir][off] = h8;
        *(short8*)&A.Bo[dir][off + 8] = l8;
    }
}

struct FusedArgs {
    const float* xq[2];   const float* xkv[2];
    const float* gq[2];   const float* btq[2];
    const float* gkv[2];  const float* btkv[2];
    const unsigned short* Bqkv[2];
    const unsigned short* Bow[2];
    const float* bq[2];   const float* bk[2];
    const float* bv[2];   const float* bo[2];
    const float* gate[2];
    float* out[2];
};

// ======================= fully-fused per-sequence kernel ==================
// 512 threads (8 waves), grid (1024, 2). Each wave owns a 32-col slab.
// launch_bounds(512,4): allocator budget 128/wave = 64 arch-VGPR + 64 AGPR.
// R6 post-mortem: kf/vb (32 regs) held across stage+GEMM busted the 64-reg
// arch half -> ~280 MB scratch. Fix: K/V live in a PERSISTENT LDS region
// above a 32 KiB half-tile staging area; fragments are loaded from LDS at
// point of use only. GEMMs run as two 32-row passes (M-split).
// LDS map (70 KiB total; 2 blocks/CU on 160 KiB):
//   [0,16K)      Ah staging (32x256)        later: Qs[w] = w*4096 (stride 32)
//   [16K,32K)    Al staging
//   [32K,52K)    Ks[4] (5120 B each)        later: Ps[w] = 32K + w*2304
//   [52K,70K)    Vs[4] (4608 B each)        (never clobbered until O phase)
__global__ __launch_bounds__(512, 4) void fused(FusedArgs P_)
{
    __shared__ char SM[71680];
    unsigned short* Ah = (unsigned short*)SM;              // [32*256]
    unsigned short* Al = (unsigned short*)(SM + 16384);
    const int dir = blockIdx.y;
    const int n = blockIdx.x, t = threadIdx.x;
    const int r0 = n * 64;
    const int w = t >> 6, l = t & 63, lm = l & 15, lq = l >> 4;

    const float* xq  = P_.xq[dir];
    const float* xkv = P_.xkv[dir];
    const unsigned short* Bq  = P_.Bqkv[dir];
    const unsigned short* BoW = P_.Bow[dir];

    // ---- staging: LN + split2 of 32 rows (half h); 8 waves x 4 rows ----
    auto stage_half = [&](const float* X, const float4& gv, const float4& b4, int h) {
        float4 xv[4];
        #pragma unroll
        for (int it = 0; it < 4; ++it)
            xv[it] = *(const float4*)(X + xrow_off(r0 + h * 32 + it * 8 + w) + l * 4);
        #pragma unroll
        for (int it = 0; it < 4; ++it) {
            int row = it * 8 + w;            // local row within half-tile
            float4 x4 = xv[it];
            float s1 = x4.x + x4.y + x4.z + x4.w;
            float s2 = x4.x * x4.x + x4.y * x4.y + x4.z * x4.z + x4.w * x4.w;
            #pragma unroll
            for (int m = 1; m < 64; m <<= 1) {
                s1 += __shfl_xor(s1, m);
                s2 += __shfl_xor(s2, m);
            }
            float mu = s1 * (1.f / 256.f);
            float rstd = rsqrtf(s2 * (1.f / 256.f) - mu * mu + 1e-5f);
            float v0 = (x4.x - mu) * rstd * gv.x + b4.x;
            float v1 = (x4.y - mu) * rstd * gv.y + b4.y;
            float v2 = (x4.z - mu) * rstd * gv.z + b4.z;
            float v3 = (x4.w - mu) * rstd * gv.w + b4.w;
            ushort4 oh, ol;
            split2(v0, oh.x, ol.x); split2(v1, oh.y, ol.y);
            split2(v2, oh.z, ol.z); split2(v3, oh.w, ol.w);
            *(ushort4*)&Ah[sw256(row, l * 4)] = oh;
            *(ushort4*)&Al[sw256(row, l * 4)] = ol;
        }
    };
    // one 32-row x 32-col GEMM pass; accumulates into acc[2h+m2][i].
    auto gemm_half = [&](f32x4 (&acc)[4][2], const unsigned short* B,
                         int nt, int ct0, int h) {
        #pragma unroll
        for (int kk = 0; kk < 8; ++kk) {
            int k0 = kk * 32 + lq * 8;
            short8 bh[2], bl[2];
            #pragma unroll
            for (int i = 0; i < 2; ++i) {
                int off = boff(nt, kk, ct0 + i, lq, lm);
                bh[i] = *(const short8*)&B[off];
                bl[i] = *(const short8*)&B[off + 8];
            }
            #pragma unroll
            for (int m2 = 0; m2 < 2; ++m2) {
                short8 ah = *(const short8*)&Ah[sw256(m2 * 16 + lm, k0)];
                short8 al = *(const short8*)&Al[sw256(m2 * 16 + lm, k0)];
                int m = 2 * h + m2;
                #pragma unroll
                for (int i = 0; i < 2; ++i) {
                    acc[m][i] = __builtin_amdgcn_mfma_f32_16x16x32_bf16(ah, bh[i], acc[m][i], 0, 0, 0);
                    acc[m][i] = __builtin_amdgcn_mfma_f32_16x16x32_bf16(al, bh[i], acc[m][i], 0, 0, 0);
                    acc[m][i] = __builtin_amdgcn_mfma_f32_16x16x32_bf16(ah, bl[i], acc[m][i], 0, 0, 0);
                }
            }
        }
    };

    // ============ K,V projection (two half-M passes) + repack ============
    {
        const float4 gv = *(const float4*)(P_.gkv[dir] + l * 4);
        const float4 b4 = *(const float4*)(P_.btkv[dir] + l * 4);
        f32x4 acc[4][2] = {};
        const int wk = w & 3;                      // slab index within K or V
        const bool isV = w >= 4;
        const int nt = (isV ? 6 : 4) + (wk >> 1);
        const int ct0 = (wk & 1) * 2;
        #pragma unroll
        for (int h = 0; h < 2; ++h) {
            stage_half(xkv, gv, b4, h);
            __syncthreads();
            gemm_half(acc, Bq, nt, ct0, h);
            __syncthreads();
        }
        // repack into persistent K/V slots (ordered vs consumers by the
        // barriers inside the Q phase below)
        const float* bias = isV ? P_.bv[dir] : P_.bk[dir];
        float bi0 = bias[wk * 32 + lm], bi1 = bias[wk * 32 + 16 + lm];
        if (!isV) {
            unsigned short* Ks = (unsigned short*)(SM + 32768 + wk * 5120);
            #pragma unroll
            for (int m = 0; m < 4; ++m)
                #pragma unroll
                for (int rg = 0; rg < 4; ++rg) {
                    int key = m * 16 + lq * 4 + rg;
                    Ks[key * 40 + lm]      = f2b(acc[m][0][rg] + bi0);
                    Ks[key * 40 + 16 + lm] = f2b(acc[m][1][rg] + bi1);
                }
        } else {
            unsigned short* Vs = (unsigned short*)(SM + 53248 + wk * 4608);
            #pragma unroll
            for (int m = 0; m < 4; ++m)
                #pragma unroll
                for (int rg = 0; rg < 4; ++rg) {
                    int key = m * 16 + lq * 4 + rg;
                    Vs[lm * 72 + key]        = f2b(acc[m][0][rg] + bi0);
                    Vs[(16 + lm) * 72 + key] = f2b(acc[m][1][rg] + bi1);
                }
        }
    }

    // ============ Q projection (two half-M passes) + attention ============
    f32x4 o[4][2] = {};
    {
        const float4 gv = *(const float4*)(P_.gq[dir] + l * 4);
        const float4 b4 = *(const float4*)(P_.btq[dir] + l * 4);
        f32x4 qacc[4][2] = {};
        #pragma unroll
        for (int h = 0; h < 2; ++h) {
            stage_half(xq, gv, b4, h);     // K/V slots above 32K untouched
            __syncthreads();
            gemm_half(qacc, Bq, w >> 1, (w & 1) * 2, h);
            __syncthreads();
        }
        // Q repack into freed staging region (wave-private, stride 32)
        unsigned short* Qs = (unsigned short*)(SM + w * 4096);
        float bq0 = P_.bq[dir][w * 32 + lm], bq1 = P_.bq[dir][w * 32 + 16 + lm];
        #pragma unroll
        for (int m = 0; m < 4; ++m)
            #pragma unroll
            for (int rg = 0; rg < 4; ++rg) {
                int row = (m * 16 + lq * 4 + rg) * 32;
                Qs[row + lm]      = f2b(qacc[m][0][rg] + bq0);
                Qs[row + 16 + lm] = f2b(qacc[m][1][rg] + bq1);
            }
        // load K fragments now (K region about to be reused for P strips)
        const int g2 = w >> 1;                      // KV head for q-head w
        short8 kf[4];
        {
            const unsigned short* Ks = (const unsigned short*)(SM + 32768 + g2 * 5120);
            #pragma unroll
            for (int nt = 0; nt < 4; ++nt)
                kf[nt] = *(const short8*)&Ks[(nt * 16 + lm) * 40 + lq * 8];
        }
        __syncthreads();   // all kf loads complete before Ps clobbers K region
        short8 vb[2][2];
        {
            const unsigned short* Vs = (const unsigned short*)(SM + 53248 + g2 * 4608);
            #pragma unroll
            for (int kt = 0; kt < 2; ++kt) {
                vb[kt][0] = *(const short8*)&Vs[lm * 72 + kt * 32 + lq * 8];
                vb[kt][1] = *(const short8*)&Vs[(16 + lm) * 72 + kt * 32 + lq * 8];
            }
        }
        unsigned short* Ps = (unsigned short*)(SM + 32768 + w * 2304); // [16][72]
        const float scale = 0.17677669529663687f;    // 1/sqrt(32)
        #pragma unroll 1
        for (int mt = 0; mt < 4; ++mt) {
            short8 qf = *(const short8*)&Qs[(mt * 16 + lm) * 32 + lq * 8];
            f32x4 s[4];
            #pragma unroll
            for (int nt = 0; nt < 4; ++nt) {
                f32x4 z = {0, 0, 0, 0};
                s[nt] = __builtin_amdgcn_mfma_f32_16x16x32_bf16(qf, kf[nt], z, 0, 0, 0);
            }
            #pragma unroll
            for (int rg = 0; rg < 4; ++rg) {
                float mx = fmaxf(fmaxf(s[0][rg], s[1][rg]),
                                 fmaxf(s[2][rg], s[3][rg]));
                #pragma unroll
                for (int msk = 1; msk < 16; msk <<= 1)
                    mx = fmaxf(mx, __shfl_xor(mx, msk));
                float p0 = __expf((s[0][rg] - mx) * scale);
                float p1 = __expf((s[1][rg] - mx) * scale);
                float p2 = __expf((s[2][rg] - mx) * scale);
                float p3 = __expf((s[3][rg] - mx) * scale);
                float sum = p0 + p1 + p2 + p3;
                #pragma unroll
                for (int msk = 1; msk < 16; msk <<= 1)
                    sum += __shfl_xor(sum, msk);
                float inv = 1.f / sum;
                int rowb = (lq * 4 + rg) * 72 + lm;
                Ps[rowb + 0]  = f2b(p0 * inv);
                Ps[rowb + 16] = f2b(p1 * inv);
                Ps[rowb + 32] = f2b(p2 * inv);
                Ps[rowb + 48] = f2b(p3 * inv);
            }
            #pragma unroll
            for (int kt = 0; kt < 2; ++kt) {
                short8 pa = *(const short8*)&Ps[lm * 72 + kt * 32 + lq * 8];
                o[mt][0] = __builtin_amdgcn_mfma_f32_16x16x32_bf16(pa, vb[kt][0], o[mt][0], 0, 0, 0);
                o[mt][1] = __builtin_amdgcn_mfma_f32_16x16x32_bf16(pa, vb[kt][1], o[mt][1], 0, 0, 0);
            }
        }
    }
    __syncthreads();   // all waves done with Qs/Ps; staging free for attn-out

    // ====== O-projection (two half-M passes) + gate + residual ======
    {
        f32x4 acc[4][2] = {};
        #pragma unroll
        for (int h = 0; h < 2; ++h) {
            #pragma unroll
            for (int m2 = 0; m2 < 2; ++m2) {
                int mt = 2 * h + m2;
                #pragma unroll
                for (int n2 = 0; n2 < 2; ++n2)
                    #pragma unroll
                    for (int rg = 0; rg < 4; ++rg) {
                        int row = m2 * 16 + lq * 4 + rg;    // local row
                        int col = w * 32 + n2 * 16 + lm;
                        unsigned short h_, l_;
                        split2(o[mt][n2][rg], h_, l_);
                        int sw = sw256(row, col);
                        Ah[sw] = h_;
                        Al[sw] = l_;
                    }
            }
            __syncthreads();
            gemm_half(acc, BoW, w >> 1, (w & 1) * 2, h);
            __syncthreads();
        }
        float sig = 1.f / (1.f + __expf(-P_.gate[dir][0]));
        const float* Xres = xq;
        float* Out = P_.out[dir];
        #pragma unroll
        for (int i = 0; i < 2; ++i) {
            int col = w * 32 + i * 16 + lm;
            float bias = P_.bo[dir][col];
            #pragma unroll
            for (int m = 0; m < 4; ++m)
                #pragma unroll
                for (int rg = 0; rg < 4; ++rg) {
                    int row = m * 16 + lq * 4 + rg;
                    int oidx = xrow_off(r0 + row) + col;
                    Out[oidx] = Xres[oidx] + sig * (acc[m][i][rg] + bias);
                }
        }
    }
}

extern "C" void kernel_launch(void* const* d_in, const int* in_sizes, int n_in,
                              void* d_out, int out_size, void* d_ws, size_t ws_size,
                              hipStream_t stream) {
    const float* x_spec = (const float*)d_in[0];
    const float* x_spat = (const float*)d_in[1];
    const float* ln_g[4] = {(const float*)d_in[2], (const float*)d_in[4],
                            (const float*)d_in[6], (const float*)d_in[8]};
    const float* ln_b[4] = {(const float*)d_in[3], (const float*)d_in[5],
                            (const float*)d_in[7], (const float*)d_in[9]};
    char* ws = (char*)d_ws;
    unsigned short* Bqkv[2] = {(unsigned short*)ws,
                               (unsigned short*)(ws + (512 << 10))};     // 2 x 512 KiB
    unsigned short* BoL[2]  = {(unsigned short*)(ws + (1024 << 10)),
                               (unsigned short*)(ws + (1280 << 10))};    // 2 x 256 KiB

    WArgs WA;
    for (int dir = 0; dir < 2; ++dir) {
        int base = 10 + dir * 8;
        WA.Wq[dir] = (const float*)d_in[base + 0];
        WA.Wk[dir] = (const float*)d_in[base + 2];
        WA.Wv[dir] = (const float*)d_in[base + 4];
        WA.Wo[dir] = (const float*)d_in[base + 6];
        WA.Bqkv[dir] = Bqkv[dir];
        WA.Bo[dir]   = BoL[dir];
    }
    w_prep<<<dim3(64, 2), 256, 0, stream>>>(WA);

    FusedArgs A;
    for (int dir = 0; dir < 2; ++dir) {
        int base = 10 + dir * 8;
        A.xq[dir]   = dir == 0 ? x_spec : x_spat;
        A.xkv[dir]  = dir == 0 ? x_spat : x_spec;
        A.gq[dir]   = dir == 0 ? ln_g[0] : ln_g[2];
        A.btq[dir]  = dir == 0 ? ln_b[0] : ln_b[2];
        A.gkv[dir]  = dir == 0 ? ln_g[3] : ln_g[1];
        A.btkv[dir] = dir == 0 ? ln_b[3] : ln_b[1];
        A.Bqkv[dir] = Bqkv[dir];
        A.Bow[dir]  = BoL[dir];
        A.bq[dir]   = (const float*)d_in[base + 1];
        A.bk[dir]   = (const float*)d_in[base + 3];
        A.bv[dir]   = (const float*)d_in[base + 5];
        A.bo[dir]   = (const float*)d_in[base + 7];
        A.gate[dir] = (const float*)d_in[26 + dir];
        A.out[dir]  = (float*)d_out + (size_t)dir * NELT;
    }
    fused<<<dim3(1024, 2), 512, 0, stream>>>(A);
}

// Round 8
// 456.130 us; speedup vs baseline: 1.4473x; 1.0375x over previous
//
#include <hip/hip_runtime.h>

typedef short short8 __attribute__((ext_vector_type(8)));
typedef float f32x4 __attribute__((ext_vector_type(4)));

#define NELT 16777216  // B*S*C*D per tensor

__device__ __forceinline__ float b2f(unsigned short u) {
    return __uint_as_float(((unsigned)u) << 16);
}
__device__ __forceinline__ unsigned short f2b(float f) {
    unsigned u = __float_as_uint(f);
    u += 0x7FFF + ((u >> 16) & 1);   // RTN-even
    return (unsigned short)(u >> 16);
}
// Markidis split: f ~= b2f(hi) + b2f(lo)
__device__ __forceinline__ void split2(float f, unsigned short& hi, unsigned short& lo) {
    unsigned short h = f2b(f);
    hi = h;
    lo = f2b(f - b2f(h));
}
// row r of the (BC*S, D) flattened view -> flat offset into x (B,S,C,D)
__device__ __forceinline__ int xrow_off(int r) {
    int n = r >> 6, s = r & 63;
    int b = n >> 7, c = n & 127;
    return (((b << 6) + s) * 128 + c) << 8;
}
// XOR-swizzled LDS element offset, [rows]x256 bf16 tile, 8-elem chunks.
__device__ __forceinline__ int sw256(int row, int k) {
    return row * 256 + ((((k >> 3) ^ (row & 7)) << 3) | (k & 7));
}
// linearized B-fragment offset (in shorts): [nt][kk][ct][lq][lm][hi8|lo8]
__device__ __forceinline__ int boff(int nt, int kk, int ct, int lq, int lm) {
    return ((((nt * 8 + kk) * 4 + ct) * 4 + lq) * 16 + lm) * 16;
}

// ---- weight pre-linearization into MFMA B-fragment order (both dirs) ----
struct WArgs {
    const float* Wq[2]; const float* Wk[2]; const float* Wv[2]; const float* Wo[2];
    unsigned short* Bqkv[2]; unsigned short* Bo[2];
};
__global__ __launch_bounds__(256) void w_prep(WArgs A)
{
    const int dir = blockIdx.y;
    const int tid = blockIdx.x * 256 + threadIdx.x;
    const int lm = tid & 15, lq = (tid >> 4) & 3, ct = (tid >> 6) & 3;
    const int kk = (tid >> 8) & 7, nt = tid >> 11;
    const int c = ct * 16 + lm;
    {
        const float* W; int ldw, col;
        if (nt < 4)      { W = A.Wq[dir]; ldw = 256; col = nt * 64 + c; }
        else if (nt < 6) { W = A.Wk[dir]; ldw = 128; col = (nt - 4) * 64 + c; }
        else             { W = A.Wv[dir]; ldw = 128; col = (nt - 6) * 64 + c; }
        short8 h8, l8;
        #pragma unroll
        for (int j = 0; j < 8; ++j) {
            int k = kk * 32 + lq * 8 + j;
            unsigned short h, l;
            split2(W[k * ldw + col], h, l);
            h8[j] = (short)h; l8[j] = (short)l;
        }
        int off = boff(nt, kk, ct, lq, lm);
        *(short8*)&A.Bqkv[dir][off] = h8;
        *(short8*)&A.Bqkv[dir][off + 8] = l8;
    }
    if (nt < 4) {
        int col = nt * 64 + c;
        short8 h8, l8;
        #pragma unroll
        for (int j = 0; j < 8; ++j) {
            int k = kk * 32 + lq * 8 + j;
            unsigned short h, l;
            split2(A.Wo[dir][k * 256 + col], h, l);
            h8[j] = (short)h; l8[j] = (short)l;
        }
        int off = boff(nt, kk, ct, lq, lm);
        *(short8*)&A.Bo[dir][off] = h8;
        *(short8*)&A.Bo[dir][off + 8] = l8;
    }
}

struct FusedArgs {
    const float* xq[2];   const float* xkv[2];
    const float* gq[2];   const float* btq[2];
    const float* gkv[2];  const float* btkv[2];
    const unsigned short* Bqkv[2];
    const unsigned short* Bow[2];
    const float* bq[2];   const float* bk[2];
    const float* bv[2];   const float* bo[2];
    const float* gate[2];
    float* out[2];
};

// ======================= fully-fused per-sequence kernel ==================
// 512 threads (8 waves), grid (1024, 2). Each wave owns a 32-col slab.
// launch_bounds(512,4): 64 arch-VGPR + 64 AGPR budget (R5-R7 ladder).
// R8: ds-latency diet.
//  - LN stage: one row per 16-lane group -> 8 shfls per wave-half (was 48)
//  - swapped QK^T (mfma(K,Q)) -> softmax reduce = 2 shfls (was 8) and
//    P written as contiguous ushort4 (was 16 scattered b16)
//  - O-projection single-pass over a 64-row staging tile (K/V/P dead then)
// LDS map (70 KiB; 2 blocks/CU):
//   [0,16K) Ah32 / [16K,32K) Al32 staging; later Qs[w]=w*4096 (stride 32)
//   [32K,52K) Ks[4] (5120 B)   later Ps[w] = 32K + w*2304
//   [52K,70K) Vs[4] (4608 B)
//   O-phase: Ah64=[0,32K), Al64=[32K,64K)
__global__ __launch_bounds__(512, 4) void fused(FusedArgs P_)
{
    __shared__ char SM[71680];
    unsigned short* Ah = (unsigned short*)SM;              // [32*256]
    unsigned short* Al = (unsigned short*)(SM + 16384);
    const int dir = blockIdx.y;
    const int n = blockIdx.x, t = threadIdx.x;
    const int r0 = n * 64;
    const int w = t >> 6, l = t & 63, lm = l & 15, lq = l >> 4;

    const float* xq  = P_.xq[dir];
    const float* xkv = P_.xkv[dir];
    const unsigned short* Bq  = P_.Bqkv[dir];
    const unsigned short* BoW = P_.Bow[dir];

    // ---- staging: LN + split2 of 32 rows (half h) ----
    // lane owns 16 elems of ONE row: row = w*4 + lq, cols lm*4 + seg*64.
    auto stage_half = [&](const float* X, const float* G, const float* BT, int h) {
        const int lrow = w * 4 + lq;
        const int xoff = xrow_off(r0 + h * 32 + lrow);
        float4 xv[4];
        #pragma unroll
        for (int seg = 0; seg < 4; ++seg)
            xv[seg] = *(const float4*)(X + xoff + lm * 4 + seg * 64);
        float s1 = 0.f, s2 = 0.f;
        #pragma unroll
        for (int seg = 0; seg < 4; ++seg) {
            float4 x4 = xv[seg];
            s1 += x4.x + x4.y + x4.z + x4.w;
            s2 += x4.x * x4.x + x4.y * x4.y + x4.z * x4.z + x4.w * x4.w;
        }
        #pragma unroll
        for (int m = 1; m < 16; m <<= 1) {
            s1 += __shfl_xor(s1, m);
            s2 += __shfl_xor(s2, m);
        }
        float mu = s1 * (1.f / 256.f);
        float rstd = rsqrtf(s2 * (1.f / 256.f) - mu * mu + 1e-5f);
        #pragma unroll
        for (int seg = 0; seg < 4; ++seg) {
            const float4 gv = *(const float4*)(G + lm * 4 + seg * 64);
            const float4 b4 = *(const float4*)(BT + lm * 4 + seg * 64);
            float4 x4 = xv[seg];
            float v0 = (x4.x - mu) * rstd * gv.x + b4.x;
            float v1 = (x4.y - mu) * rstd * gv.y + b4.y;
            float v2 = (x4.z - mu) * rstd * gv.z + b4.z;
            float v3 = (x4.w - mu) * rstd * gv.w + b4.w;
            ushort4 oh, ol;
            split2(v0, oh.x, ol.x); split2(v1, oh.y, ol.y);
            split2(v2, oh.z, ol.z); split2(v3, oh.w, ol.w);
            int sw = sw256(lrow, lm * 4 + seg * 64);
            *(ushort4*)&Ah[sw] = oh;
            *(ushort4*)&Al[sw] = ol;
        }
    };
    // one 32-row x 32-col GEMM pass; accumulates into acc[2h+m2][i].
    auto gemm_half = [&](f32x4 (&acc)[4][2], const unsigned short* B,
                         int nt, int ct0, int h) {
        #pragma unroll
        for (int kk = 0; kk < 8; ++kk) {
            int k0 = kk * 32 + lq * 8;
            short8 bh[2], bl[2];
            #pragma unroll
            for (int i = 0; i < 2; ++i) {
                int off = boff(nt, kk, ct0 + i, lq, lm);
                bh[i] = *(const short8*)&B[off];
                bl[i] = *(const short8*)&B[off + 8];
            }
            #pragma unroll
            for (int m2 = 0; m2 < 2; ++m2) {
                short8 ah = *(const short8*)&Ah[sw256(m2 * 16 + lm, k0)];
                short8 al = *(const short8*)&Al[sw256(m2 * 16 + lm, k0)];
                int m = 2 * h + m2;
                #pragma unroll
                for (int i = 0; i < 2; ++i) {
                    acc[m][i] = __builtin_amdgcn_mfma_f32_16x16x32_bf16(ah, bh[i], acc[m][i], 0, 0, 0);
                    acc[m][i] = __builtin_amdgcn_mfma_f32_16x16x32_bf16(al, bh[i], acc[m][i], 0, 0, 0);
                    acc[m][i] = __builtin_amdgcn_mfma_f32_16x16x32_bf16(ah, bl[i], acc[m][i], 0, 0, 0);
                }
            }
        }
    };

    // ============ K,V projection (two half-M passes) + repack ============
    {
        const float* G  = P_.gkv[dir];
        const float* BT = P_.btkv[dir];
        f32x4 acc[4][2] = {};
        const int wk = w & 3;                      // slab index within K or V
        const bool isV = w >= 4;
        const int nt = (isV ? 6 : 4) + (wk >> 1);
        const int ct0 = (wk & 1) * 2;
        #pragma unroll
        for (int h = 0; h < 2; ++h) {
            stage_half(xkv, G, BT, h);
            __syncthreads();
            gemm_half(acc, Bq, nt, ct0, h);
            __syncthreads();
        }
        const float* bias = isV ? P_.bv[dir] : P_.bk[dir];
        float bi0 = bias[wk * 32 + lm], bi1 = bias[wk * 32 + 16 + lm];
        if (!isV) {
            unsigned short* Ks = (unsigned short*)(SM + 32768 + wk * 5120);
            #pragma unroll
            for (int m = 0; m < 4; ++m)
                #pragma unroll
                for (int rg = 0; rg < 4; ++rg) {
                    int key = m * 16 + lq * 4 + rg;
                    Ks[key * 40 + lm]      = f2b(acc[m][0][rg] + bi0);
                    Ks[key * 40 + 16 + lm] = f2b(acc[m][1][rg] + bi1);
                }
        } else {
            unsigned short* Vs = (unsigned short*)(SM + 53248 + wk * 4608);
            #pragma unroll
            for (int m = 0; m < 4; ++m)
                #pragma unroll
                for (int rg = 0; rg < 4; ++rg) {
                    int key = m * 16 + lq * 4 + rg;
                    Vs[lm * 72 + key]        = f2b(acc[m][0][rg] + bi0);
                    Vs[(16 + lm) * 72 + key] = f2b(acc[m][1][rg] + bi1);
                }
        }
    }

    // ============ Q projection (two half-M passes) + attention ============
    f32x4 o[4][2] = {};
    {
        const float* G  = P_.gq[dir];
        const float* BT = P_.btq[dir];
        f32x4 qacc[4][2] = {};
        #pragma unroll
        for (int h = 0; h < 2; ++h) {
            stage_half(xq, G, BT, h);      // K/V slots above 32K untouched
            __syncthreads();
            gemm_half(qacc, Bq, w >> 1, (w & 1) * 2, h);
            __syncthreads();
        }
        // Q repack into freed staging region (wave-private, stride 32)
        unsigned short* Qs = (unsigned short*)(SM + w * 4096);
        float bq0 = P_.bq[dir][w * 32 + lm], bq1 = P_.bq[dir][w * 32 + 16 + lm];
        #pragma unroll
        for (int m = 0; m < 4; ++m)
            #pragma unroll
            for (int rg = 0; rg < 4; ++rg) {
                int row = (m * 16 + lq * 4 + rg) * 32;
                Qs[row + lm]      = f2b(qacc[m][0][rg] + bq0);
                Qs[row + 16 + lm] = f2b(qacc[m][1][rg] + bq1);
            }
        // load K fragments now (K region about to be reused for P strips)
        const int g2 = w >> 1;                      // KV head for q-head w
        short8 kf[4];
        {
            const unsigned short* Ks = (const unsigned short*)(SM + 32768 + g2 * 5120);
            #pragma unroll
            for (int nt = 0; nt < 4; ++nt)
                kf[nt] = *(const short8*)&Ks[(nt * 16 + lm) * 40 + lq * 8];
        }
        __syncthreads();   // all kf loads complete before Ps clobbers K region
        short8 vb[2][2];
        {
            const unsigned short* Vs = (const unsigned short*)(SM + 53248 + g2 * 4608);
            #pragma unroll
            for (int kt = 0; kt < 2; ++kt) {
                vb[kt][0] = *(const short8*)&Vs[lm * 72 + kt * 32 + lq * 8];
                vb[kt][1] = *(const short8*)&Vs[(16 + lm) * 72 + kt * 32 + lq * 8];
            }
        }
        // swapped QK^T: s = mfma(K, Q) -> lane holds S^T[key][query=lm]
        // keys per lane: nt*16 + lq*4 + rg. Softmax reduce = 2 shfls.
        unsigned short* Ps = (unsigned short*)(SM + 32768 + w * 2304); // [16 q][72]
        const float scale = 0.17677669529663687f;    // 1/sqrt(32)
        #pragma unroll 1
        for (int mt = 0; mt < 4; ++mt) {
            short8 qf = *(const short8*)&Qs[(mt * 16 + lm) * 32 + lq * 8];
            f32x4 s[4];
            #pragma unroll
            for (int nt = 0; nt < 4; ++nt) {
                f32x4 z = {0, 0, 0, 0};
                s[nt] = __builtin_amdgcn_mfma_f32_16x16x32_bf16(kf[nt], qf, z, 0, 0, 0);
            }
            float mx = s[0][0];
            #pragma unroll
            for (int nt = 0; nt < 4; ++nt)
                #pragma unroll
                for (int rg = 0; rg < 4; ++rg)
                    mx = fmaxf(mx, s[nt][rg]);
            mx = fmaxf(mx, __shfl_xor(mx, 16));
            mx = fmaxf(mx, __shfl_xor(mx, 32));
            float sum = 0.f;
            #pragma unroll
            for (int nt = 0; nt < 4; ++nt)
                #pragma unroll
                for (int rg = 0; rg < 4; ++rg) {
                    s[nt][rg] = __expf((s[nt][rg] - mx) * scale);
                    sum += s[nt][rg];
                }
            sum += __shfl_xor(sum, 16);
            sum += __shfl_xor(sum, 32);
            float inv = 1.f / sum;
            #pragma unroll
            for (int nt = 0; nt < 4; ++nt) {
                ushort4 pw;
                pw.x = f2b(s[nt][0] * inv);
                pw.y = f2b(s[nt][1] * inv);
                pw.z = f2b(s[nt][2] * inv);
                pw.w = f2b(s[nt][3] * inv);
                *(ushort4*)&Ps[lm * 72 + nt * 16 + lq * 4] = pw;
            }
            #pragma unroll
            for (int kt = 0; kt < 2; ++kt) {
                short8 pa = *(const short8*)&Ps[lm * 72 + kt * 32 + lq * 8];
                o[mt][0] = __builtin_amdgcn_mfma_f32_16x16x32_bf16(pa, vb[kt][0], o[mt][0], 0, 0, 0);
                o[mt][1] = __builtin_amdgcn_mfma_f32_16x16x32_bf16(pa, vb[kt][1], o[mt][1], 0, 0, 0);
            }
        }
    }
    __syncthreads();   // all waves done with Qs/Ps/K/V; full LDS free

    // ====== O-projection: single 64-row pass + gate + residual ======
    {
        unsigned short* AhF = (unsigned short*)SM;             // [64*256]
        unsigned short* AlF = (unsigned short*)(SM + 32768);
        #pragma unroll
        for (int mt = 0; mt < 4; ++mt)
            #pragma unroll
            for (int n2 = 0; n2 < 2; ++n2)
                #pragma unroll
                for (int rg = 0; rg < 4; ++rg) {
                    int row = mt * 16 + lq * 4 + rg;
                    int col = w * 32 + n2 * 16 + lm;
                    unsigned short h_, l_;
                    split2(o[mt][n2][rg], h_, l_);
                    int sw = sw256(row, col);
                    AhF[sw] = h_;
                    AlF[sw] = l_;
                }
        __syncthreads();
        f32x4 acc[4][2] = {};
        const int nt = w >> 1, ct0 = (w & 1) * 2;
        #pragma unroll
        for (int kk = 0; kk < 8; ++kk) {
            int k0 = kk * 32 + lq * 8;
            short8 bh[2], bl[2];
            #pragma unroll
            for (int i = 0; i < 2; ++i) {
                int off = boff(nt, kk, ct0 + i, lq, lm);
                bh[i] = *(const short8*)&BoW[off];
                bl[i] = *(const short8*)&BoW[off + 8];
            }
            #pragma unroll
            for (int m = 0; m < 4; ++m) {
                short8 ah = *(const short8*)&AhF[sw256(m * 16 + lm, k0)];
                short8 al = *(const short8*)&AlF[sw256(m * 16 + lm, k0)];
                #pragma unroll
                for (int i = 0; i < 2; ++i) {
                    acc[m][i] = __builtin_amdgcn_mfma_f32_16x16x32_bf16(ah, bh[i], acc[m][i], 0, 0, 0);
                    acc[m][i] = __builtin_amdgcn_mfma_f32_16x16x32_bf16(al, bh[i], acc[m][i], 0, 0, 0);
                    acc[m][i] = __builtin_amdgcn_mfma_f32_16x16x32_bf16(ah, bl[i], acc[m][i], 0, 0, 0);
                }
            }
        }
        float sig = 1.f / (1.f + __expf(-P_.gate[dir][0]));
        const float* Xres = xq;
        float* Out = P_.out[dir];
        #pragma unroll
        for (int i = 0; i < 2; ++i) {
            int col = w * 32 + i * 16 + lm;
            float bias = P_.bo[dir][col];
            #pragma unroll
            for (int m = 0; m < 4; ++m)
                #pragma unroll
                for (int rg = 0; rg < 4; ++rg) {
                    int row = m * 16 + lq * 4 + rg;
                    int oidx = xrow_off(r0 + row) + col;
                    Out[oidx] = Xres[oidx] + sig * (acc[m][i][rg] + bias);
                }
        }
    }
}

extern "C" void kernel_launch(void* const* d_in, const int* in_sizes, int n_in,
                              void* d_out, int out_size, void* d_ws, size_t ws_size,
                              hipStream_t stream) {
    const float* x_spec = (const float*)d_in[0];
    const float* x_spat = (const float*)d_in[1];
    const float* ln_g[4] = {(const float*)d_in[2], (const float*)d_in[4],
                            (const float*)d_in[6], (const float*)d_in[8]};
    const float* ln_b[4] = {(const float*)d_in[3], (const float*)d_in[5],
                            (const float*)d_in[7], (const float*)d_in[9]};
    char* ws = (char*)d_ws;
    unsigned short* Bqkv[2] = {(unsigned short*)ws,
                               (unsigned short*)(ws + (512 << 10))};     // 2 x 512 KiB
    unsigned short* BoL[2]  = {(unsigned short*)(ws + (1024 << 10)),
                               (unsigned short*)(ws + (1280 << 10))};    // 2 x 256 KiB

    WArgs WA;
    for (int dir = 0; dir < 2; ++dir) {
        int base = 10 + dir * 8;
        WA.Wq[dir] = (const float*)d_in[base + 0];
        WA.Wk[dir] = (const float*)d_in[base + 2];
        WA.Wv[dir] = (const float*)d_in[base + 4];
        WA.Wo[dir] = (const float*)d_in[base + 6];
        WA.Bqkv[dir] = Bqkv[dir];
        WA.Bo[dir]   = BoL[dir];
    }
    w_prep<<<dim3(64, 2), 256, 0, stream>>>(WA);

    FusedArgs A;
    for (int dir = 0; dir < 2; ++dir) {
        int base = 10 + dir * 8;
        A.xq[dir]   = dir == 0 ? x_spec : x_spat;
        A.xkv[dir]  = dir == 0 ? x_spat : x_spec;
        A.gq[dir]   = dir == 0 ? ln_g[0] : ln_g[2];
        A.btq[dir]  = dir == 0 ? ln_b[0] : ln_b[2];
        A.gkv[dir]  = dir == 0 ? ln_g[3] : ln_g[1];
        A.btkv[dir] = dir == 0 ? ln_b[3] : ln_b[1];
        A.Bqkv[dir] = Bqkv[dir];
        A.Bow[dir]  = BoL[dir];
        A.bq[dir]   = (const float*)d_in[base + 1];
        A.bk[dir]   = (const float*)d_in[base + 3];
        A.bv[dir]   = (const float*)d_in[base + 5];
        A.bo[dir]   = (const float*)d_in[base + 7];
        A.gate[dir] = (const float*)d_in[26 + dir];
        A.out[dir]  = (float*)d_out + (size_t)dir * NELT;
    }
    fused<<<dim3(1024, 2), 512, 0, stream>>>(A);
}